// Round 11
// baseline (647.721 us; speedup 1.0000x reference)
//
#include <hip/hip_runtime.h>
#include <math.h>
#include <stdint.h>

namespace {
constexpr int kB = 2, kN = 6, kC = 64, kD = 41, kH = 32, kW = 88;
constexpr int kHW = kH * kW;                  // 2816
constexpr int kBN = kB * kN;                  // 12
constexpr int kCols = kBN * kHW;              // 33792 softmax columns
constexpr int kNX = 200;
constexpr int kPts = kBN * kD * kHW;          // 1,385,472 points
constexpr int kPtsPerB = kN * kD * kHW;       // 692736
constexpr int kRows = kB * kNX;               // 400 CSR rows (b, ix)

constexpr int kCntBlks = kPts / 1024;                   // 1353 (exact)
constexpr int kTransBlks = kBN * (kHW / 64);            // 528
constexpr int kStatsBlks = (kCols + 255) / 256;         // 132
constexpr int kPrepBlks = kCntBlks + kTransBlks + kStatsBlks;
}  // namespace

// Blocks fp-contraction (hipcc -ffp-contract=fast would fuse mul+sub into
// fma and change voxel binning vs the per-op f32 numpy reference).
#define FP_BARRIER(x) asm volatile("" : "+v"(x))

// Fused prep kernel, block-range partitioned (all parts independent):
//   [0, kCntBlks)       : voxel-bin 1024 pts/block + per-row LDS histogram
//   [+kTransBlks)       : feat [bn][c][hw] -> featT [bn][hw][c]
//   [+kStatsBlks)       : softmax stats (col max, sum of exp)
__global__ void __launch_bounds__(256) lss_prep(
    const float* __restrict__ feat, float* __restrict__ featT,
    const float* __restrict__ logits, float* __restrict__ cmax,
    float* __restrict__ csum, const float* __restrict__ geom,
    uint16_t* __restrict__ vox16, unsigned* __restrict__ cnt) {
  __shared__ float t[64][65];
  __shared__ unsigned shist[kRows];
  int blk = blockIdx.x;
  int tid = threadIdx.x;
  if (blk < kCntBlks) {
    // ---- count: per-op f32 voxel binning (proven R7 semantics) ----
    for (int r = tid; r < kRows; r += 256) shist[r] = 0;
    __syncthreads();
    int base = blk * 1024;
#pragma unroll
    for (int j = 0; j < 4; ++j) {
      int i = base + tid + j * 256;           // stride-256 -> coalesced
      size_t g = (size_t)i * 3;
      float gx = geom[g + 0];
      float gy = geom[g + 1];
      float gz = geom[g + 2];
      float px = __fmul_rn(gx, 100.0f); FP_BARRIER(px);
      float py = __fmul_rn(gy, 100.0f); FP_BARRIER(py);
      float pz = __fmul_rn(gz, 20.0f);  FP_BARRIER(pz);
      float wx = __fsub_rn(px, 50.0f);  FP_BARRIER(wx);
      float wy = __fsub_rn(py, 50.0f);  FP_BARRIER(wy);
      float wz = __fsub_rn(pz, 10.0f);  FP_BARRIER(wz);
      float tx = __fadd_rn(wx, 50.0f);  FP_BARRIER(tx);
      float ty = __fadd_rn(wy, 50.0f);  FP_BARRIER(ty);
      float tz = __fadd_rn(wz, 10.0f);  FP_BARRIER(tz);
      float qx = __fdiv_rn(tx, 0.5f);   FP_BARRIER(qx);
      float qy = __fdiv_rn(ty, 0.5f);   FP_BARRIER(qy);
      float qz = __fdiv_rn(tz, 20.0f);  FP_BARRIER(qz);
      int ix = (int)floorf(qx);
      int iy = (int)floorf(qy);
      int iz = (int)floorf(qz);
      uint16_t v = 0xFFFFu;
      if ((unsigned)ix < (unsigned)kNX && (unsigned)iy < (unsigned)kNX &&
          (unsigned)iz < 1u) {
        v = (uint16_t)((ix << 8) | iy);       // ix,iy < 256 each
        int b = i / kPtsPerB;
        atomicAdd(&shist[b * kNX + ix], 1u);  // LDS, cheap
      }
      vox16[i] = v;
    }
    __syncthreads();
    for (int r = tid; r < kRows; r += 256)    // ~370 nonzero/block
      if (shist[r]) atomicAdd(&cnt[r], shist[r]);
  } else if (blk < kCntBlks + kTransBlks) {
    // ---- transpose (LDS tile) ----
    int tb = blk - kCntBlks;
    int bn = tb / 44;                  // kHW = 44*64
    int hw0 = (tb % 44) * 64;
    const float* src = feat + (size_t)bn * kC * kHW;
#pragma unroll
    for (int p = 0; p < 16; ++p) {     // read coalesced in hw
      int c = p * 4 + (tid >> 6);
      int hw = tid & 63;
      t[hw][c] = src[(size_t)c * kHW + hw0 + hw];
    }
    __syncthreads();
    float* dst = featT + ((size_t)bn * kHW + hw0) * kC;
#pragma unroll
    for (int p = 0; p < 16; ++p) {     // write coalesced in c
      int hw = p * 4 + (tid >> 6);
      int c = tid & 63;
      dst[(size_t)hw * kC + c] = t[hw][c];
    }
  } else {
    // ---- softmax stats ----
    int col = (blk - kCntBlks - kTransBlks) * 256 + tid;
    if (col >= kCols) return;
    int bn = col / kHW;
    int hw = col - bn * kHW;
    const float* p = logits + (size_t)bn * kD * kHW + hw;
    float m = -INFINITY;
#pragma unroll
    for (int d = 0; d < kD; ++d) m = fmaxf(m, p[(size_t)d * kHW]);
    float s = 0.0f;
#pragma unroll
    for (int d = 0; d < kD; ++d) s += expf(p[(size_t)d * kHW] - m);
    cmax[col] = m;
    csum[col] = s;
  }
}

// Row allocator: exclusive scan of cnt[400] -> seg (starts) and cur
// (running cursors). One tiny block.
__global__ void __launch_bounds__(512) lss_alloc(
    const unsigned* __restrict__ cnt, unsigned* __restrict__ seg,
    unsigned* __restrict__ cur) {
  __shared__ unsigned lds[512];
  int t = threadIdx.x;
  unsigned c = (t < kRows) ? cnt[t] : 0u;
  lds[t] = c;
  __syncthreads();
  for (int o = 1; o < 512; o <<= 1) {
    unsigned x = (t >= o) ? lds[t - o] : 0u;
    __syncthreads();
    lds[t] += x;
    __syncthreads();
  }
  if (t < kRows) {
    seg[t] = lds[t] - c;
    cur[t] = lds[t] - c;
  }
}

// Fill row-CSR entries {iy|col, wgt}. Per-block LDS histogram + ONE global
// reservation per touched row -> same-row entries from a block are
// contiguous -> line-dense scatter (kills the 64B/entry write amplification).
__global__ void __launch_bounds__(256) lss_fill(
    const float* __restrict__ logits, const uint16_t* __restrict__ vox16,
    const float* __restrict__ cmax, const float* __restrict__ csum,
    unsigned* __restrict__ cur, uint2* __restrict__ list) {
  __shared__ unsigned shist[kRows];
  __shared__ unsigned sbase[kRows];
  int tid = threadIdx.x;
  int base = blockIdx.x * 1024;
  for (int r = tid; r < kRows; r += 256) shist[r] = 0;
  __syncthreads();
#pragma unroll
  for (int j = 0; j < 4; ++j) {
    int i = base + tid + j * 256;
    unsigned p = vox16[i];
    if (p != 0xFFFFu) {
      int row = (i / kPtsPerB) * kNX + (int)(p >> 8);
      atomicAdd(&shist[row], 1u);
    }
  }
  __syncthreads();
  for (int r = tid; r < kRows; r += 256)
    if (shist[r]) sbase[r] = atomicAdd(&cur[r], shist[r]);
  __syncthreads();
#pragma unroll
  for (int j = 0; j < 4; ++j) {
    int i = base + tid + j * 256;
    unsigned p = vox16[i];
    if (p == 0xFFFFu) continue;
    int row = (i / kPtsPerB) * kNX + (int)(p >> 8);
    int hw = i % kHW;
    int bn = i / (kD * kHW);
    int col = bn * kHW + hw;
    float wgt = expf(logits[i] - cmax[col]) / csum[col];
    unsigned pos = atomicAdd(&sbase[row], 1u);  // LDS cursor -> global pos
    list[pos] = make_uint2(((p & 255u) << 16) | (unsigned)col,
                           __float_as_uint(wgt));
  }
}

// Row gather: one block per (b, ix) row. Accumulate the 200x64 BEV tile in
// LDS (pad 65 -> conflict-free), wave-per-entry (lane = channel), then one
// coalesced tile store. Every output cell written -> no output memset.
__global__ void __launch_bounds__(1024) lss_rowgather(
    const unsigned* __restrict__ seg, const unsigned* __restrict__ cnt,
    const uint2* __restrict__ list, const float* __restrict__ featT,
    float* __restrict__ out) {
  __shared__ float acc[kNX * 65];  // 52,000 B
  int tid = threadIdx.x;
  for (int idx = tid; idx < kNX * 65; idx += 1024) acc[idx] = 0.0f;
  __syncthreads();
  int r = blockIdx.x;
  int b = r / kNX, ix = r - (r / kNX) * kNX;
  unsigned s = seg[r];
  unsigned e = s + cnt[r];
  int wv = tid >> 6, lane = tid & 63;
  unsigned k = s + wv;
  for (; k + 16 < e; k += 32) {        // 2 entries in flight per wave
    uint2 a = list[k];
    uint2 q = list[k + 16];
    float fa = featT[(size_t)(a.x & 0xFFFFu) * kC + lane];
    float fq = featT[(size_t)(q.x & 0xFFFFu) * kC + lane];
    atomicAdd(&acc[(a.x >> 16) * 65 + lane], __uint_as_float(a.y) * fa);
    atomicAdd(&acc[(q.x >> 16) * 65 + lane], __uint_as_float(q.y) * fq);
  }
  if (k < e) {
    uint2 a = list[k];
    float fa = featT[(size_t)(a.x & 0xFFFFu) * kC + lane];
    atomicAdd(&acc[(a.x >> 16) * 65 + lane], __uint_as_float(a.y) * fa);
  }
  __syncthreads();
  float* op = out + ((size_t)b * kC * kNX + ix) * kNX;  // + c*kNX*kNX + iy
  for (int idx = tid; idx < kNX * kC; idx += 1024) {
    int c = idx / kNX, iy = idx - (idx / kNX) * kNX;    // consecutive iy
    op[(size_t)c * kNX * kNX + iy] = acc[iy * 65 + c];
  }
}

extern "C" void kernel_launch(void* const* d_in, const int* in_sizes, int n_in,
                              void* d_out, int out_size, void* d_ws,
                              size_t ws_size, hipStream_t stream) {
  const float* feat = (const float*)d_in[0];
  const float* logits = (const float*)d_in[1];
  const float* geom = (const float*)d_in[2];
  float* out = (float*)d_out;

  // Workspace layout (8B-aligned first): total ~22.8 MB
  char* w = (char*)d_ws;
  uint2* list = (uint2*)w;        w += (size_t)kPts * 8;            // 11.08MB
  float* featT = (float*)w;       w += (size_t)kBN * kHW * kC * 4;  // 8.65MB
  float* cmax = (float*)w;        w += (size_t)kCols * 4;
  float* csum = (float*)w;        w += (size_t)kCols * 4;
  unsigned* cnt = (unsigned*)w;   w += (size_t)kRows * 4;
  unsigned* seg = (unsigned*)w;   w += (size_t)kRows * 4;
  unsigned* cur = (unsigned*)w;   w += (size_t)kRows * 4;
  uint16_t* vox16 = (uint16_t*)w;                                   // 2.77MB

  hipMemsetAsync(cnt, 0, (size_t)kRows * sizeof(unsigned), stream);

  lss_prep<<<kPrepBlks, 256, 0, stream>>>(feat, featT, logits, cmax, csum,
                                          geom, vox16, cnt);
  lss_alloc<<<1, 512, 0, stream>>>(cnt, seg, cur);
  lss_fill<<<kCntBlks, 256, 0, stream>>>(logits, vox16, cmax, csum, cur,
                                         list);
  lss_rowgather<<<kRows, 1024, 0, stream>>>(seg, cnt, list, featT, out);
}

// Round 12
// 176.031 us; speedup vs baseline: 3.6796x; 3.6796x over previous
//
#include <hip/hip_runtime.h>
#include <math.h>
#include <stdint.h>

namespace {
constexpr int kB = 2, kN = 6, kC = 64, kD = 41, kH = 32, kW = 88;
constexpr int kHW = kH * kW;                  // 2816
constexpr int kBN = kB * kN;                  // 12
constexpr int kCols = kBN * kHW;              // 33792 softmax columns
constexpr int kNX = 200;
constexpr int kPts = kBN * kD * kHW;          // 1,385,472 points
constexpr int kPtsPerB = kN * kD * kHW;       // 692736
constexpr int kRows = kB * kNX;               // 400 CSR rows (b, ix)
constexpr int kCap = 4608;                    // row capacity (mean 3464, sd~59)

constexpr int kCntBlks = kPts / 1024;                   // 1353 (exact)
constexpr int kTransBlks = kBN * (kHW / 64);            // 528
constexpr int kStatsBlks = (kCols + 255) / 256;         // 132
constexpr int kPrepBlks = kCntBlks + kTransBlks + kStatsBlks;
}  // namespace

// Blocks fp-contraction (hipcc -ffp-contract=fast would fuse mul+sub into
// fma and change voxel binning vs the per-op f32 numpy reference).
#define FP_BARRIER(x) asm volatile("" : "+v"(x))

// Fused prep kernel, block-range partitioned (all parts independent):
//   [0, kCntBlks)       : voxel-bin 1024 pts/block + per-row LDS histogram
//   [+kTransBlks)       : feat [bn][c][hw] -> featT [bn][hw][c]
//   [+kStatsBlks)       : softmax stats (col max, sum of exp)
__global__ void __launch_bounds__(256) lss_prep(
    const float* __restrict__ feat, float* __restrict__ featT,
    const float* __restrict__ logits, float* __restrict__ cmax,
    float* __restrict__ csum, const float* __restrict__ geom,
    uint16_t* __restrict__ vox16, unsigned* __restrict__ cnt) {
  __shared__ float t[64][65];
  __shared__ unsigned shist[kRows];
  int blk = blockIdx.x;
  int tid = threadIdx.x;
  if (blk < kCntBlks) {
    // ---- count: per-op f32 voxel binning (proven R7 semantics) ----
    for (int r = tid; r < kRows; r += 256) shist[r] = 0;
    __syncthreads();
    int base = blk * 1024;
#pragma unroll
    for (int j = 0; j < 4; ++j) {
      int i = base + tid + j * 256;           // stride-256 -> coalesced
      size_t g = (size_t)i * 3;
      float gx = geom[g + 0];
      float gy = geom[g + 1];
      float gz = geom[g + 2];
      float px = __fmul_rn(gx, 100.0f); FP_BARRIER(px);
      float py = __fmul_rn(gy, 100.0f); FP_BARRIER(py);
      float pz = __fmul_rn(gz, 20.0f);  FP_BARRIER(pz);
      float wx = __fsub_rn(px, 50.0f);  FP_BARRIER(wx);
      float wy = __fsub_rn(py, 50.0f);  FP_BARRIER(wy);
      float wz = __fsub_rn(pz, 10.0f);  FP_BARRIER(wz);
      float tx = __fadd_rn(wx, 50.0f);  FP_BARRIER(tx);
      float ty = __fadd_rn(wy, 50.0f);  FP_BARRIER(ty);
      float tz = __fadd_rn(wz, 10.0f);  FP_BARRIER(tz);
      float qx = __fdiv_rn(tx, 0.5f);   FP_BARRIER(qx);
      float qy = __fdiv_rn(ty, 0.5f);   FP_BARRIER(qy);
      float qz = __fdiv_rn(tz, 20.0f);  FP_BARRIER(qz);
      int ix = (int)floorf(qx);
      int iy = (int)floorf(qy);
      int iz = (int)floorf(qz);
      uint16_t v = 0xFFFFu;
      if ((unsigned)ix < (unsigned)kNX && (unsigned)iy < (unsigned)kNX &&
          (unsigned)iz < 1u) {
        v = (uint16_t)((ix << 8) | iy);       // ix,iy < 256 each
        int b = i / kPtsPerB;
        atomicAdd(&shist[b * kNX + ix], 1u);  // LDS int atomic, native
      }
      vox16[i] = v;
    }
    __syncthreads();
    for (int r = tid; r < kRows; r += 256)    // ~370 nonzero/block
      if (shist[r]) atomicAdd(&cnt[r], shist[r]);
  } else if (blk < kCntBlks + kTransBlks) {
    // ---- transpose (LDS tile) ----
    int tb = blk - kCntBlks;
    int bn = tb / 44;                  // kHW = 44*64
    int hw0 = (tb % 44) * 64;
    const float* src = feat + (size_t)bn * kC * kHW;
#pragma unroll
    for (int p = 0; p < 16; ++p) {     // read coalesced in hw
      int c = p * 4 + (tid >> 6);
      int hw = tid & 63;
      t[hw][c] = src[(size_t)c * kHW + hw0 + hw];
    }
    __syncthreads();
    float* dst = featT + ((size_t)bn * kHW + hw0) * kC;
#pragma unroll
    for (int p = 0; p < 16; ++p) {     // write coalesced in c
      int hw = p * 4 + (tid >> 6);
      int c = tid & 63;
      dst[(size_t)hw * kC + c] = t[hw][c];
    }
  } else {
    // ---- softmax stats ----
    int col = (blk - kCntBlks - kTransBlks) * 256 + tid;
    if (col >= kCols) return;
    int bn = col / kHW;
    int hw = col - bn * kHW;
    const float* p = logits + (size_t)bn * kD * kHW + hw;
    float m = -INFINITY;
#pragma unroll
    for (int d = 0; d < kD; ++d) m = fmaxf(m, p[(size_t)d * kHW]);
    float s = 0.0f;
#pragma unroll
    for (int d = 0; d < kD; ++d) s += expf(p[(size_t)d * kHW] - m);
    cmax[col] = m;
    csum[col] = s;
  }
}

// Row allocator: exclusive scan of cnt[400] -> seg (starts) and cur
// (running cursors). One tiny block.
__global__ void __launch_bounds__(512) lss_alloc(
    const unsigned* __restrict__ cnt, unsigned* __restrict__ seg,
    unsigned* __restrict__ cur) {
  __shared__ unsigned lds[512];
  int t = threadIdx.x;
  unsigned c = (t < kRows) ? cnt[t] : 0u;
  lds[t] = c;
  __syncthreads();
  for (int o = 1; o < 512; o <<= 1) {
    unsigned x = (t >= o) ? lds[t - o] : 0u;
    __syncthreads();
    lds[t] += x;
    __syncthreads();
  }
  if (t < kRows) {
    seg[t] = lds[t] - c;
    cur[t] = lds[t] - c;
  }
}

// Fill row-CSR entries {iy|col, wgt}. Per-block LDS histogram + ONE global
// reservation per touched row -> same-row entries from a block are
// contiguous -> line-dense scatter (proven ~15us in R11).
__global__ void __launch_bounds__(256) lss_fill(
    const float* __restrict__ logits, const uint16_t* __restrict__ vox16,
    const float* __restrict__ cmax, const float* __restrict__ csum,
    unsigned* __restrict__ cur, uint2* __restrict__ list) {
  __shared__ unsigned shist[kRows];
  __shared__ unsigned sbase[kRows];
  int tid = threadIdx.x;
  int base = blockIdx.x * 1024;
  for (int r = tid; r < kRows; r += 256) shist[r] = 0;
  __syncthreads();
#pragma unroll
  for (int j = 0; j < 4; ++j) {
    int i = base + tid + j * 256;
    unsigned p = vox16[i];
    if (p != 0xFFFFu) {
      int row = (i / kPtsPerB) * kNX + (int)(p >> 8);
      atomicAdd(&shist[row], 1u);
    }
  }
  __syncthreads();
  for (int r = tid; r < kRows; r += 256)
    if (shist[r]) sbase[r] = atomicAdd(&cur[r], shist[r]);
  __syncthreads();
#pragma unroll
  for (int j = 0; j < 4; ++j) {
    int i = base + tid + j * 256;
    unsigned p = vox16[i];
    if (p == 0xFFFFu) continue;
    int row = (i / kPtsPerB) * kNX + (int)(p >> 8);
    int hw = i % kHW;
    int bn = i / (kD * kHW);
    int col = bn * kHW + hw;
    float wgt = expf(logits[i] - cmax[col]) / csum[col];
    unsigned pos = atomicAdd(&sbase[row], 1u);  // LDS cursor -> global pos
    list[pos] = make_uint2(((p & 255u) << 16) | (unsigned)col,
                           __float_as_uint(wgt));
  }
}

// Row gather v2: one block per (b, ix) row. Counting-sort the row's entries
// by iy in LDS (int atomics only), then each wave owns 13 iy-bins and
// accumulates in REGISTERS (lane = channel) -> no float atomics anywhere.
// Every output cell written -> no output memset.
__global__ void __launch_bounds__(1024) lss_rowgather(
    const unsigned* __restrict__ seg, const unsigned* __restrict__ cnt,
    const uint2* __restrict__ list, const float* __restrict__ featT,
    float* __restrict__ out) {
  __shared__ uint2 sl[kCap];            // 36,864 B sorted entries
  __shared__ unsigned hist[256];        // histogram / scan buffer
  __shared__ unsigned off[kNX + 1];     // bin start offsets
  __shared__ unsigned curb[kNX];        // scatter cursors
  int tid = threadIdx.x;
  int r = blockIdx.x;
  int b = r / kNX, ix = r - (r / kNX) * kNX;
  unsigned s0 = seg[r];
  unsigned n = cnt[r];
  unsigned ns = min(n, (unsigned)kCap);

  if (tid < 256) hist[tid] = 0;
  __syncthreads();
  // pass 1: histogram iy (coalesced global reads, native LDS int atomics)
  for (unsigned k = tid; k < ns; k += 1024)
    atomicAdd(&hist[list[s0 + k].x >> 16], 1u);
  __syncthreads();
  unsigned c0 = (tid < 256) ? hist[tid] : 0u;
  // inclusive Hillis-Steele scan over 256 bins
  for (int o = 1; o < 256; o <<= 1) {
    unsigned x = 0;
    if (tid < 256 && tid >= o) x = hist[tid - o];
    __syncthreads();
    if (tid < 256) hist[tid] += x;
    __syncthreads();
  }
  if (tid < 200) {
    unsigned st = hist[tid] - c0;       // exclusive
    off[tid] = st;
    curb[tid] = st;
  }
  if (tid == 0) off[kNX] = ns;
  __syncthreads();
  // pass 2: scatter into sorted LDS list
  for (unsigned k = tid; k < ns; k += 1024) {
    uint2 a = list[s0 + k];
    unsigned pos = atomicAdd(&curb[a.x >> 16], 1u);
    sl[pos] = a;
  }
  __syncthreads();
  // phase 3: wave w owns bins [w*13, w*13+13); register accumulation
  int wv = tid >> 6, lane = tid & 63;
  int iy0 = wv * 13, iy1 = min(iy0 + 13, kNX);
  float* op = out + ((size_t)(b * kC + lane) * kNX + ix) * kNX;
  for (int iy = iy0; iy < iy1; ++iy) {
    unsigned k = off[iy], e = off[iy + 1];
    float acc = 0.0f;
    for (; k + 4 <= e; k += 4) {        // 4 independent featT loads in flight
      uint2 e0 = sl[k + 0];
      uint2 e1 = sl[k + 1];
      uint2 e2 = sl[k + 2];
      uint2 e3 = sl[k + 3];
      float f0 = featT[(size_t)(e0.x & 0xFFFFu) * kC + lane];
      float f1 = featT[(size_t)(e1.x & 0xFFFFu) * kC + lane];
      float f2 = featT[(size_t)(e2.x & 0xFFFFu) * kC + lane];
      float f3 = featT[(size_t)(e3.x & 0xFFFFu) * kC + lane];
      acc += __uint_as_float(e0.y) * f0;
      acc += __uint_as_float(e1.y) * f1;
      acc += __uint_as_float(e2.y) * f2;
      acc += __uint_as_float(e3.y) * f3;
    }
    for (; k < e; ++k) {
      uint2 a = sl[k];
      acc += __uint_as_float(a.y) * featT[(size_t)(a.x & 0xFFFFu) * kC + lane];
    }
    op[iy] = acc;                        // plain store; L2 absorbs
  }
  // overflow tail (n > kCap; statistically never at n~3464+-60): add after
  // all bulk stores of this block (other blocks never touch this row).
  if (n > (unsigned)kCap) {
    __syncthreads();
    for (unsigned k = ns + wv; k < n; k += 16) {
      uint2 a = list[s0 + k];
      float f = featT[(size_t)(a.x & 0xFFFFu) * kC + lane];
      unsafeAtomicAdd(&op[a.x >> 16], __uint_as_float(a.y) * f);
    }
  }
}

extern "C" void kernel_launch(void* const* d_in, const int* in_sizes, int n_in,
                              void* d_out, int out_size, void* d_ws,
                              size_t ws_size, hipStream_t stream) {
  const float* feat = (const float*)d_in[0];
  const float* logits = (const float*)d_in[1];
  const float* geom = (const float*)d_in[2];
  float* out = (float*)d_out;

  // Workspace layout (8B-aligned first): total ~22.8 MB
  char* w = (char*)d_ws;
  uint2* list = (uint2*)w;        w += (size_t)kPts * 8;            // 11.08MB
  float* featT = (float*)w;       w += (size_t)kBN * kHW * kC * 4;  // 8.65MB
  float* cmax = (float*)w;        w += (size_t)kCols * 4;
  float* csum = (float*)w;        w += (size_t)kCols * 4;
  unsigned* cnt = (unsigned*)w;   w += (size_t)kRows * 4;
  unsigned* seg = (unsigned*)w;   w += (size_t)kRows * 4;
  unsigned* cur = (unsigned*)w;   w += (size_t)kRows * 4;
  uint16_t* vox16 = (uint16_t*)w;                                   // 2.77MB

  hipMemsetAsync(cnt, 0, (size_t)kRows * sizeof(unsigned), stream);

  lss_prep<<<kPrepBlks, 256, 0, stream>>>(feat, featT, logits, cmax, csum,
                                          geom, vox16, cnt);
  lss_alloc<<<1, 512, 0, stream>>>(cnt, seg, cur);
  lss_fill<<<kCntBlks, 256, 0, stream>>>(logits, vox16, cmax, csum, cur,
                                         list);
  lss_rowgather<<<kRows, 1024, 0, stream>>>(seg, cnt, list, featT, out);
}

// Round 13
// 118.397 us; speedup vs baseline: 5.4708x; 1.4868x over previous
//
#include <hip/hip_runtime.h>
#include <math.h>
#include <stdint.h>

namespace {
constexpr int kB = 2, kN = 6, kC = 64, kD = 41, kH = 32, kW = 88;
constexpr int kHW = kH * kW;                  // 2816
constexpr int kBN = kB * kN;                  // 12
constexpr int kCols = kBN * kHW;              // 33792 softmax columns
constexpr int kNX = 200;
constexpr int kVox = kNX * kNX;               // 40000
constexpr int kPts = kBN * kD * kHW;          // 1,385,472 points
constexpr int kPtsPerB = kN * kD * kHW;       // 692736
constexpr int kRows2 = kB * kNX * 2;          // 800 CSR rows (b, ix, iy-half)
constexpr int kHCap = 2400;                   // half-row cap (mean 1732, sd~41)

constexpr int kCntBlks = kPts / 1024;                   // 1353 (exact)
constexpr int kTransBlks = kBN * (kHW / 64);            // 528
constexpr int kStatsBlks = (kCols + 255) / 256;         // 132
constexpr int kPrepBlks = kCntBlks + kTransBlks + kStatsBlks;
}  // namespace

// Blocks fp-contraction (hipcc -ffp-contract=fast would fuse mul+sub into
// fma and change voxel binning vs the per-op f32 numpy reference).
#define FP_BARRIER(x) asm volatile("" : "+v"(x))

// Fused prep kernel, block-range partitioned (all parts independent):
//   [0, kCntBlks)       : voxel-bin 1024 pts/block + per-row2 LDS histogram
//   [+kTransBlks)       : feat [bn][c][hw] -> featT [bn][hw][c]
//   [+kStatsBlks)       : softmax stats (col max, sum of exp)
__global__ void __launch_bounds__(256) lss_prep(
    const float* __restrict__ feat, float* __restrict__ featT,
    const float* __restrict__ logits, float* __restrict__ cmax,
    float* __restrict__ csum, const float* __restrict__ geom,
    uint16_t* __restrict__ vox16, unsigned* __restrict__ cnt) {
  __shared__ float t[64][65];
  __shared__ unsigned shist[kRows2];
  int blk = blockIdx.x;
  int tid = threadIdx.x;
  if (blk < kCntBlks) {
    // ---- count: per-op f32 voxel binning (proven R7 semantics) ----
    for (int r = tid; r < kRows2; r += 256) shist[r] = 0;
    __syncthreads();
    int base = blk * 1024;
#pragma unroll
    for (int j = 0; j < 4; ++j) {
      int i = base + tid + j * 256;           // stride-256 -> coalesced
      size_t g = (size_t)i * 3;
      float gx = geom[g + 0];
      float gy = geom[g + 1];
      float gz = geom[g + 2];
      float px = __fmul_rn(gx, 100.0f); FP_BARRIER(px);
      float py = __fmul_rn(gy, 100.0f); FP_BARRIER(py);
      float pz = __fmul_rn(gz, 20.0f);  FP_BARRIER(pz);
      float wx = __fsub_rn(px, 50.0f);  FP_BARRIER(wx);
      float wy = __fsub_rn(py, 50.0f);  FP_BARRIER(wy);
      float wz = __fsub_rn(pz, 10.0f);  FP_BARRIER(wz);
      float tx = __fadd_rn(wx, 50.0f);  FP_BARRIER(tx);
      float ty = __fadd_rn(wy, 50.0f);  FP_BARRIER(ty);
      float tz = __fadd_rn(wz, 10.0f);  FP_BARRIER(tz);
      float qx = __fdiv_rn(tx, 0.5f);   FP_BARRIER(qx);
      float qy = __fdiv_rn(ty, 0.5f);   FP_BARRIER(qy);
      float qz = __fdiv_rn(tz, 20.0f);  FP_BARRIER(qz);
      int ix = (int)floorf(qx);
      int iy = (int)floorf(qy);
      int iz = (int)floorf(qz);
      uint16_t v = 0xFFFFu;
      if ((unsigned)ix < (unsigned)kNX && (unsigned)iy < (unsigned)kNX &&
          (unsigned)iz < 1u) {
        v = (uint16_t)((ix << 8) | iy);       // ix,iy < 256 each
        int b = i / kPtsPerB;
        int row2 = ((b * kNX + ix) << 1) + (iy >= 100);
        atomicAdd(&shist[row2], 1u);          // LDS int atomic, native
      }
      vox16[i] = v;
    }
    __syncthreads();
    for (int r = tid; r < kRows2; r += 256)
      if (shist[r]) atomicAdd(&cnt[r], shist[r]);
  } else if (blk < kCntBlks + kTransBlks) {
    // ---- transpose (LDS tile) ----
    int tb = blk - kCntBlks;
    int bn = tb / 44;                  // kHW = 44*64
    int hw0 = (tb % 44) * 64;
    const float* src = feat + (size_t)bn * kC * kHW;
#pragma unroll
    for (int p = 0; p < 16; ++p) {     // read coalesced in hw
      int c = p * 4 + (tid >> 6);
      int hw = tid & 63;
      t[hw][c] = src[(size_t)c * kHW + hw0 + hw];
    }
    __syncthreads();
    float* dst = featT + ((size_t)bn * kHW + hw0) * kC;
#pragma unroll
    for (int p = 0; p < 16; ++p) {     // write coalesced in c
      int hw = p * 4 + (tid >> 6);
      int c = tid & 63;
      dst[(size_t)hw * kC + c] = t[hw][c];
    }
  } else {
    // ---- softmax stats ----
    int col = (blk - kCntBlks - kTransBlks) * 256 + tid;
    if (col >= kCols) return;
    int bn = col / kHW;
    int hw = col - bn * kHW;
    const float* p = logits + (size_t)bn * kD * kHW + hw;
    float m = -INFINITY;
#pragma unroll
    for (int d = 0; d < kD; ++d) m = fmaxf(m, p[(size_t)d * kHW]);
    float s = 0.0f;
#pragma unroll
    for (int d = 0; d < kD; ++d) s += expf(p[(size_t)d * kHW] - m);
    cmax[col] = m;
    csum[col] = s;
  }
}

// Row allocator: exclusive scan of cnt[800] -> seg (starts) and cur
// (running cursors). One tiny block.
__global__ void __launch_bounds__(1024) lss_alloc(
    const unsigned* __restrict__ cnt, unsigned* __restrict__ seg,
    unsigned* __restrict__ cur) {
  __shared__ unsigned lds[1024];
  int t = threadIdx.x;
  unsigned c = (t < kRows2) ? cnt[t] : 0u;
  lds[t] = c;
  __syncthreads();
  for (int o = 1; o < 1024; o <<= 1) {
    unsigned x = (t >= o) ? lds[t - o] : 0u;
    __syncthreads();
    lds[t] += x;
    __syncthreads();
  }
  if (t < kRows2) {
    seg[t] = lds[t] - c;
    cur[t] = lds[t] - c;
  }
}

// Fill row-CSR entries {iy|col, wgt}. Per-block LDS histogram + ONE global
// reservation per touched row -> same-row entries from a block are
// contiguous -> line-dense scatter (proven in R11/R12).
__global__ void __launch_bounds__(256) lss_fill(
    const float* __restrict__ logits, const uint16_t* __restrict__ vox16,
    const float* __restrict__ cmax, const float* __restrict__ csum,
    unsigned* __restrict__ cur, uint2* __restrict__ list) {
  __shared__ unsigned shist[kRows2];
  __shared__ unsigned sbase[kRows2];
  int tid = threadIdx.x;
  int base = blockIdx.x * 1024;
  for (int r = tid; r < kRows2; r += 256) shist[r] = 0;
  __syncthreads();
#pragma unroll
  for (int j = 0; j < 4; ++j) {
    int i = base + tid + j * 256;
    unsigned p = vox16[i];
    if (p != 0xFFFFu) {
      int row2 = (((i / kPtsPerB) * kNX + (int)(p >> 8)) << 1) +
                 ((p & 255u) >= 100);
      atomicAdd(&shist[row2], 1u);
    }
  }
  __syncthreads();
  for (int r = tid; r < kRows2; r += 256)
    if (shist[r]) sbase[r] = atomicAdd(&cur[r], shist[r]);
  __syncthreads();
#pragma unroll
  for (int j = 0; j < 4; ++j) {
    int i = base + tid + j * 256;
    unsigned p = vox16[i];
    if (p == 0xFFFFu) continue;
    int row2 = (((i / kPtsPerB) * kNX + (int)(p >> 8)) << 1) +
               ((p & 255u) >= 100);
    int hw = i % kHW;
    int bn = i / (kD * kHW);
    int col = bn * kHW + hw;
    float wgt = expf(logits[i] - cmax[col]) / csum[col];
    unsigned pos = atomicAdd(&sbase[row2], 1u);  // LDS cursor -> global pos
    list[pos] = make_uint2(((p & 255u) << 16) | (unsigned)col,
                           __float_as_uint(wgt));
  }
}

// Row gather v3: one 512-thread block per (b, ix, iy-half). Counting-sort
// the ~1732 entries by iy in LDS, then each wave owns 13 iy-bins. Lanes
// split 4 groups x 16: group g loads float4 of entry k+g -> ONE wave-load
// serves 4 entries (1/4 address-path cost), 2-deep unroll = 8 entries in
// flight. Butterfly shfl_xor(16,32) reduces groups; accT staged in LDS
// (stride 67 = conflict-free), one coalesced tile store. No f32 atomics.
__global__ void __launch_bounds__(512) lss_rowgather(
    const unsigned* __restrict__ seg, const unsigned* __restrict__ cnt,
    const uint2* __restrict__ list, const float* __restrict__ featT,
    float* __restrict__ out) {
  __shared__ uint2 sl[kHCap];           // 19.2 KB sorted entries
  __shared__ float accT[100 * 67];      // 26.8 KB (stride 67: bank-free)
  __shared__ unsigned hist[128];
  __shared__ unsigned off[101];
  __shared__ unsigned curb[100];
  int tid = threadIdx.x;
  int r2 = blockIdx.x;
  int half = r2 & 1;
  int r = r2 >> 1;
  int b = r / kNX, ix = r - (r / kNX) * kNX;
  int iyb = half * 100;
  unsigned s0 = seg[r2];
  unsigned n = cnt[r2];
  unsigned ns = min(n, (unsigned)kHCap);

  if (tid < 128) hist[tid] = 0;
  __syncthreads();
  // pass 1: histogram local iy
  for (unsigned k = tid; k < ns; k += 512)
    atomicAdd(&hist[(list[s0 + k].x >> 16) - iyb], 1u);
  __syncthreads();
  unsigned c0 = (tid < 128) ? hist[tid] : 0u;
  for (int o = 1; o < 128; o <<= 1) {   // inclusive scan over 128 bins
    unsigned x = (tid < 128 && tid >= o) ? hist[tid - o] : 0u;
    __syncthreads();
    if (tid < 128) hist[tid] += x;
    __syncthreads();
  }
  if (tid < 100) {
    unsigned st = hist[tid] - c0;
    off[tid] = st;
    curb[tid] = st;
  }
  if (tid == 0) off[100] = ns;
  __syncthreads();
  // pass 2: scatter into sorted LDS list
  for (unsigned k = tid; k < ns; k += 512) {
    uint2 a = list[s0 + k];
    unsigned pos = atomicAdd(&curb[(a.x >> 16) - iyb], 1u);
    sl[pos] = a;
  }
  __syncthreads();
  // phase 3: wave wv owns bins [wv*13, ..); 4x16 lane split
  int wv = tid >> 6, lane = tid & 63;
  int g = lane >> 4, sub = lane & 15;
  int ly0 = wv * 13, ly1 = min(ly0 + 13, 100);
  for (int ly = ly0; ly < ly1; ++ly) {
    unsigned k = off[ly], e = off[ly + 1];
    float a0 = 0, a1 = 0, a2 = 0, a3 = 0;
    unsigned kk = k + g;
    for (; kk + 4 < e; kk += 8) {       // 2 rounds in flight
      uint2 ea = sl[kk];
      uint2 eb = sl[kk + 4];
      const float4 fa = *(const float4*)(featT +
          ((size_t)(ea.x & 0xFFFFu) << 6) + (sub << 2));
      const float4 fb = *(const float4*)(featT +
          ((size_t)(eb.x & 0xFFFFu) << 6) + (sub << 2));
      float wa = __uint_as_float(ea.y), wb = __uint_as_float(eb.y);
      a0 += wa * fa.x; a1 += wa * fa.y; a2 += wa * fa.z; a3 += wa * fa.w;
      a0 += wb * fb.x; a1 += wb * fb.y; a2 += wb * fb.z; a3 += wb * fb.w;
    }
    if (kk < e) {
      uint2 ea = sl[kk];
      const float4 fa = *(const float4*)(featT +
          ((size_t)(ea.x & 0xFFFFu) << 6) + (sub << 2));
      float wa = __uint_as_float(ea.y);
      a0 += wa * fa.x; a1 += wa * fa.y; a2 += wa * fa.z; a3 += wa * fa.w;
    }
    // butterfly reduce across the 4 lane groups
    a0 += __shfl_xor(a0, 16); a0 += __shfl_xor(a0, 32);
    a1 += __shfl_xor(a1, 16); a1 += __shfl_xor(a1, 32);
    a2 += __shfl_xor(a2, 16); a2 += __shfl_xor(a2, 32);
    a3 += __shfl_xor(a3, 16); a3 += __shfl_xor(a3, 32);
    if (g == 0) {
      float* dst = &accT[ly * 67 + (sub << 2)];
      dst[0] = a0; dst[1] = a1; dst[2] = a2; dst[3] = a3;
    }
  }
  __syncthreads();
  // coalesced tile store (every cell written -> no output memset)
  float* op = out + ((size_t)b * kC * kNX + ix) * kNX + iyb;
  for (int idx = tid; idx < kC * 100; idx += 512) {
    int c = idx / 100, iy = idx - c * 100;
    op[(size_t)c * kVox + iy] = accT[iy * 67 + c];
  }
  // overflow tail (n > kHCap; ~16 sigma out, statistically never)
  if (n > (unsigned)kHCap) {
    __syncthreads();
    for (unsigned k = ns + wv * 64 + lane; k < n; k += 512) {
      uint2 a = list[s0 + k];
      float w = __uint_as_float(a.y);
      int iy = (int)(a.x >> 16) - iyb;
      const float* fr = featT + ((size_t)(a.x & 0xFFFFu) << 6);
      for (int c = 0; c < kC; ++c)
        unsafeAtomicAdd(&op[(size_t)c * kVox + iy], w * fr[c]);
    }
  }
}

extern "C" void kernel_launch(void* const* d_in, const int* in_sizes, int n_in,
                              void* d_out, int out_size, void* d_ws,
                              size_t ws_size, hipStream_t stream) {
  const float* feat = (const float*)d_in[0];
  const float* logits = (const float*)d_in[1];
  const float* geom = (const float*)d_in[2];
  float* out = (float*)d_out;

  // Workspace layout (8B-aligned first): total ~22.8 MB (proven fit)
  char* w = (char*)d_ws;
  uint2* list = (uint2*)w;        w += (size_t)kPts * 8;            // 11.08MB
  float* featT = (float*)w;       w += (size_t)kBN * kHW * kC * 4;  // 8.65MB
  float* cmax = (float*)w;        w += (size_t)kCols * 4;
  float* csum = (float*)w;        w += (size_t)kCols * 4;
  unsigned* cnt = (unsigned*)w;   w += (size_t)kRows2 * 4;
  unsigned* seg = (unsigned*)w;   w += (size_t)kRows2 * 4;
  unsigned* cur = (unsigned*)w;   w += (size_t)kRows2 * 4;
  uint16_t* vox16 = (uint16_t*)w;                                   // 2.77MB

  hipMemsetAsync(cnt, 0, (size_t)kRows2 * sizeof(unsigned), stream);

  lss_prep<<<kPrepBlks, 256, 0, stream>>>(feat, featT, logits, cmax, csum,
                                          geom, vox16, cnt);
  lss_alloc<<<1, 1024, 0, stream>>>(cnt, seg, cur);
  lss_fill<<<kCntBlks, 256, 0, stream>>>(logits, vox16, cmax, csum, cur,
                                         list);
  lss_rowgather<<<kRows2, 512, 0, stream>>>(seg, cnt, list, featT, out);
}

// Round 14
// 108.770 us; speedup vs baseline: 5.9549x; 1.0885x over previous
//
#include <hip/hip_runtime.h>
#include <math.h>
#include <stdint.h>

namespace {
constexpr int kB = 2, kN = 6, kC = 64, kD = 41, kH = 32, kW = 88;
constexpr int kHW = kH * kW;                  // 2816
constexpr int kBN = kB * kN;                  // 12
constexpr int kCols = kBN * kHW;              // 33792 softmax columns
constexpr int kNX = 200;
constexpr int kVox = kNX * kNX;               // 40000
constexpr int kPts = kBN * kD * kHW;          // 1,385,472 points
constexpr int kPtsPerB = kN * kD * kHW;       // 692736
constexpr int kRows2 = kB * kNX * 2;          // 800 rows (b, ix, iy-half)
constexpr int kCap2 = 2176;                   // fixed row cap (+10.7 sigma)
constexpr int kOvfCap = 8192;                 // overflow list (never used)

constexpr int kBinBlks = kPts / 1024;         // 1353 (exact)
constexpr int kTransBlks = kBN * (kHW / 64);  // 528
constexpr int kStatsBlks = (kCols + 255) / 256;  // 132
constexpr int kPrepBlks = kTransBlks + kStatsBlks;
}  // namespace

// Blocks fp-contraction (hipcc -ffp-contract=fast would fuse mul+sub into
// fma and change voxel binning vs the per-op f32 numpy reference).
#define FP_BARRIER(x) asm volatile("" : "+v"(x))

// Kernel A: transpose + softmax stats (both independent of binning).
__global__ void __launch_bounds__(256) lss_prep(
    const float* __restrict__ feat, float* __restrict__ featT,
    const float* __restrict__ logits, float* __restrict__ cmax,
    float* __restrict__ csum) {
  __shared__ float t[64][65];
  int blk = blockIdx.x;
  int tid = threadIdx.x;
  if (blk < kTransBlks) {
    // ---- transpose feat [bn][c][hw] -> featT [bn][hw][c] ----
    int bn = blk / 44;                 // kHW = 44*64
    int hw0 = (blk % 44) * 64;
    const float* src = feat + (size_t)bn * kC * kHW;
#pragma unroll
    for (int p = 0; p < 16; ++p) {     // read coalesced in hw
      int c = p * 4 + (tid >> 6);
      int hw = tid & 63;
      t[hw][c] = src[(size_t)c * kHW + hw0 + hw];
    }
    __syncthreads();
    float* dst = featT + ((size_t)bn * kHW + hw0) * kC;
#pragma unroll
    for (int p = 0; p < 16; ++p) {     // write coalesced in c
      int hw = p * 4 + (tid >> 6);
      int c = tid & 63;
      dst[(size_t)hw * kC + c] = t[hw][c];
    }
  } else {
    // ---- softmax stats: column max and sum(exp) over D ----
    int col = (blk - kTransBlks) * 256 + tid;
    if (col >= kCols) return;
    int bn = col / kHW;
    int hw = col - bn * kHW;
    const float* p = logits + (size_t)bn * kD * kHW + hw;
    float m = -INFINITY;
#pragma unroll
    for (int d = 0; d < kD; ++d) m = fmaxf(m, p[(size_t)d * kHW]);
    float s = 0.0f;
#pragma unroll
    for (int d = 0; d < kD; ++d) s += expf(p[(size_t)d * kHW] - m);
    cmax[col] = m;
    csum[col] = s;
  }
}

// Kernel B: fused bin + weight + fill. 1024 pts/block. Voxel-bin (proven
// barriered per-op f32), cache packed vox in LDS, per-row2 LDS histogram,
// ONE global reservation atomicAdd(cnt[row2], h) per touched row, then
// scatter entries {iy|col, wgt} into the row's FIXED segment r2*kCap2.
// Fixed caps kill the alloc/scan kernel; overflow (never, +10.7 sigma)
// goes to a small global list handled in rowgather.
__global__ void __launch_bounds__(256) lss_binfill(
    const float* __restrict__ geom, const float* __restrict__ logits,
    const float* __restrict__ cmax, const float* __restrict__ csum,
    unsigned* __restrict__ cnt, uint2* __restrict__ list,
    unsigned* __restrict__ ovf_cnt, uint4* __restrict__ ovf) {
  __shared__ unsigned shist[kRows2];
  __shared__ unsigned sbase[kRows2];
  __shared__ uint16_t svox[1024];
  int tid = threadIdx.x;
  int base = blockIdx.x * 1024;
  for (int r = tid; r < kRows2; r += 256) shist[r] = 0;
  __syncthreads();
#pragma unroll
  for (int j = 0; j < 4; ++j) {
    int i = base + tid + j * 256;             // stride-256 -> coalesced
    size_t g = (size_t)i * 3;
    float gx = geom[g + 0];
    float gy = geom[g + 1];
    float gz = geom[g + 2];
    float px = __fmul_rn(gx, 100.0f); FP_BARRIER(px);
    float py = __fmul_rn(gy, 100.0f); FP_BARRIER(py);
    float pz = __fmul_rn(gz, 20.0f);  FP_BARRIER(pz);
    float wx = __fsub_rn(px, 50.0f);  FP_BARRIER(wx);
    float wy = __fsub_rn(py, 50.0f);  FP_BARRIER(wy);
    float wz = __fsub_rn(pz, 10.0f);  FP_BARRIER(wz);
    float tx = __fadd_rn(wx, 50.0f);  FP_BARRIER(tx);
    float ty = __fadd_rn(wy, 50.0f);  FP_BARRIER(ty);
    float tz = __fadd_rn(wz, 10.0f);  FP_BARRIER(tz);
    float qx = __fdiv_rn(tx, 0.5f);   FP_BARRIER(qx);
    float qy = __fdiv_rn(ty, 0.5f);   FP_BARRIER(qy);
    float qz = __fdiv_rn(tz, 20.0f);  FP_BARRIER(qz);
    int ix = (int)floorf(qx);
    int iy = (int)floorf(qy);
    int iz = (int)floorf(qz);
    uint16_t v = 0xFFFFu;
    if ((unsigned)ix < (unsigned)kNX && (unsigned)iy < (unsigned)kNX &&
        (unsigned)iz < 1u) {
      v = (uint16_t)((ix << 8) | iy);
      int b = i / kPtsPerB;
      int row2 = ((b * kNX + ix) << 1) + (iy >= 100);
      atomicAdd(&shist[row2], 1u);            // LDS int atomic, native
    }
    svox[tid + j * 256] = v;
  }
  __syncthreads();
  for (int r = tid; r < kRows2; r += 256)
    if (shist[r]) sbase[r] = atomicAdd(&cnt[r], shist[r]);
  __syncthreads();
#pragma unroll
  for (int j = 0; j < 4; ++j) {
    int i = base + tid + j * 256;
    unsigned p = svox[tid + j * 256];
    if (p == 0xFFFFu) continue;
    int b = i / kPtsPerB;
    int row2 = ((b * kNX + (int)(p >> 8)) << 1) + ((p & 255u) >= 100);
    int hw = i % kHW;
    int bn = i / (kD * kHW);
    int col = bn * kHW + hw;
    float wgt = expf(logits[i] - cmax[col]) / csum[col];
    unsigned pos = atomicAdd(&sbase[row2], 1u);  // LDS cursor
    unsigned key = ((p & 255u) << 16) | (unsigned)col;
    if (pos < (unsigned)kCap2) {
      list[(size_t)row2 * kCap2 + pos] =
          make_uint2(key, __float_as_uint(wgt));
    } else {                                   // never taken (+10.7 sigma)
      unsigned o = atomicAdd(ovf_cnt, 1u);
      if (o < (unsigned)kOvfCap)
        ovf[o] = make_uint4((unsigned)row2, key, __float_as_uint(wgt), 0u);
    }
  }
}

// Row gather: one 512-thread block per (b, ix, iy-half). Counting-sort the
// ~1732 entries by iy in LDS, then each wave owns 13 iy-bins. Lanes split
// 4 groups x 16: group g loads float4 of entry k+g -> one wave-load serves
// 4 entries; 2-deep unroll = 8 in flight. Butterfly shfl_xor(16,32)
// reduces groups; accT staged in LDS (stride 67), one coalesced store.
__global__ void __launch_bounds__(512) lss_rowgather(
    const unsigned* __restrict__ cnt, const uint2* __restrict__ list,
    const float* __restrict__ featT, float* __restrict__ out,
    const unsigned* __restrict__ ovf_cnt, const uint4* __restrict__ ovf) {
  __shared__ uint2 sl[kCap2];           // 17.4 KB sorted entries
  __shared__ float accT[100 * 67];      // 26.8 KB (stride 67: bank-free)
  __shared__ unsigned hist[128];
  __shared__ unsigned off[101];
  __shared__ unsigned curb[100];
  int tid = threadIdx.x;
  int r2 = blockIdx.x;
  int half = r2 & 1;
  int r = r2 >> 1;
  int b = r / kNX, ix = r - (r / kNX) * kNX;
  int iyb = half * 100;
  size_t s0 = (size_t)r2 * kCap2;
  unsigned n = cnt[r2];
  unsigned ns = min(n, (unsigned)kCap2);

  if (tid < 128) hist[tid] = 0;
  __syncthreads();
  // pass 1: histogram local iy
  for (unsigned k = tid; k < ns; k += 512)
    atomicAdd(&hist[(list[s0 + k].x >> 16) - iyb], 1u);
  __syncthreads();
  unsigned c0 = (tid < 128) ? hist[tid] : 0u;
  for (int o = 1; o < 128; o <<= 1) {   // inclusive scan over 128 bins
    unsigned x = (tid < 128 && tid >= o) ? hist[tid - o] : 0u;
    __syncthreads();
    if (tid < 128) hist[tid] += x;
    __syncthreads();
  }
  if (tid < 100) {
    unsigned st = hist[tid] - c0;
    off[tid] = st;
    curb[tid] = st;
  }
  if (tid == 0) off[100] = ns;
  __syncthreads();
  // pass 2: scatter into sorted LDS list
  for (unsigned k = tid; k < ns; k += 512) {
    uint2 a = list[s0 + k];
    unsigned pos = atomicAdd(&curb[(a.x >> 16) - iyb], 1u);
    sl[pos] = a;
  }
  __syncthreads();
  // phase 3: wave wv owns bins [wv*13, ..); 4x16 lane split
  int wv = tid >> 6, lane = tid & 63;
  int g = lane >> 4, sub = lane & 15;
  int ly0 = wv * 13, ly1 = min(ly0 + 13, 100);
  for (int ly = ly0; ly < ly1; ++ly) {
    unsigned k = off[ly], e = off[ly + 1];
    float a0 = 0, a1 = 0, a2 = 0, a3 = 0;
    unsigned kk = k + g;
    for (; kk + 4 < e; kk += 8) {       // 2 rounds in flight
      uint2 ea = sl[kk];
      uint2 eb = sl[kk + 4];
      const float4 fa = *(const float4*)(featT +
          ((size_t)(ea.x & 0xFFFFu) << 6) + (sub << 2));
      const float4 fb = *(const float4*)(featT +
          ((size_t)(eb.x & 0xFFFFu) << 6) + (sub << 2));
      float wa = __uint_as_float(ea.y), wb = __uint_as_float(eb.y);
      a0 += wa * fa.x; a1 += wa * fa.y; a2 += wa * fa.z; a3 += wa * fa.w;
      a0 += wb * fb.x; a1 += wb * fb.y; a2 += wb * fb.z; a3 += wb * fb.w;
    }
    if (kk < e) {
      uint2 ea = sl[kk];
      const float4 fa = *(const float4*)(featT +
          ((size_t)(ea.x & 0xFFFFu) << 6) + (sub << 2));
      float wa = __uint_as_float(ea.y);
      a0 += wa * fa.x; a1 += wa * fa.y; a2 += wa * fa.z; a3 += wa * fa.w;
    }
    // butterfly reduce across the 4 lane groups
    a0 += __shfl_xor(a0, 16); a0 += __shfl_xor(a0, 32);
    a1 += __shfl_xor(a1, 16); a1 += __shfl_xor(a1, 32);
    a2 += __shfl_xor(a2, 16); a2 += __shfl_xor(a2, 32);
    a3 += __shfl_xor(a3, 16); a3 += __shfl_xor(a3, 32);
    if (g == 0) {
      float* dst = &accT[ly * 67 + (sub << 2)];
      dst[0] = a0; dst[1] = a1; dst[2] = a2; dst[3] = a3;
    }
  }
  __syncthreads();
  // overflow epilogue (never taken; kept for correctness)
  unsigned ovfn = min(*ovf_cnt, (unsigned)kOvfCap);
  if (ovfn > 0) {
    for (unsigned k = tid; k < ovfn; k += 512) {
      uint4 a = ovf[k];
      if (a.x != (unsigned)r2) continue;
      int ly = (int)(a.y >> 16) - iyb;
      const float* fr = featT + ((size_t)(a.y & 0xFFFFu) << 6);
      float w = __uint_as_float(a.z);
      for (int c = 0; c < kC; ++c) atomicAdd(&accT[ly * 67 + c], w * fr[c]);
    }
    __syncthreads();
  }
  // coalesced tile store (every cell written -> no output memset)
  float* op = out + ((size_t)b * kC * kNX + ix) * kNX + iyb;
  for (int idx = tid; idx < kC * 100; idx += 512) {
    int c = idx / 100, iy = idx - c * 100;
    op[(size_t)c * kVox + iy] = accT[iy * 67 + c];
  }
}

extern "C" void kernel_launch(void* const* d_in, const int* in_sizes, int n_in,
                              void* d_out, int out_size, void* d_ws,
                              size_t ws_size, hipStream_t stream) {
  const float* feat = (const float*)d_in[0];
  const float* logits = (const float*)d_in[1];
  const float* geom = (const float*)d_in[2];
  float* out = (float*)d_out;

  // Workspace layout (16B-aligned first): total ~23.1 MB (< 23.75 proven)
  char* w = (char*)d_ws;
  uint2* list = (uint2*)w;        w += (size_t)kRows2 * kCap2 * 8;  // 13.93MB
  float* featT = (float*)w;       w += (size_t)kBN * kHW * kC * 4;  // 8.65MB
  uint4* ovf = (uint4*)w;         w += (size_t)kOvfCap * 16;        // 128KB
  float* cmax = (float*)w;        w += (size_t)kCols * 4;
  float* csum = (float*)w;        w += (size_t)kCols * 4;
  unsigned* cnt = (unsigned*)w;   w += (size_t)kRows2 * 4;
  unsigned* ovf_cnt = (unsigned*)w;

  // Zero cnt + ovf_cnt in one memset (adjacent).
  hipMemsetAsync(cnt, 0, (size_t)kRows2 * 4 + 4, stream);

  lss_prep<<<kPrepBlks, 256, 0, stream>>>(feat, featT, logits, cmax, csum);
  lss_binfill<<<kBinBlks, 256, 0, stream>>>(geom, logits, cmax, csum, cnt,
                                            list, ovf_cnt, ovf);
  lss_rowgather<<<kRows2, 512, 0, stream>>>(cnt, list, featT, out, ovf_cnt,
                                            ovf);
}

// Round 15
// 67.108 us; speedup vs baseline: 9.6519x; 1.6208x over previous
//
#include <hip/hip_runtime.h>
#include <math.h>
#include <stdint.h>

namespace {
constexpr int kB = 2, kN = 6, kC = 64, kD = 41, kH = 32, kW = 88;
constexpr int kHW = kH * kW;                  // 2816
constexpr int kBN = kB * kN;                  // 12
constexpr int kNX = 200;
constexpr int kVox = kNX * kNX;               // 40000
constexpr int kPts = kBN * kD * kHW;          // 1,385,472
constexpr int kRows4 = kB * kNX * 4;          // 1600 rows (b, ix, iy-quarter)
constexpr int kCap4 = 1120;                   // mean 866, +8.6 sigma
constexpr int kOvfCap = 4096;                 // overflow list (never used)

constexpr int kTiles = kBN * (kHW / 64);      // 528 (bn, hw-tile-64)
constexpr int kFusedBlks = kTiles * 2;        // [0,528) transpose | [528,1056) binfill
}  // namespace

// Blocks fp-contraction (hipcc -ffp-contract=fast would fuse mul+sub into
// fma and change voxel binning vs the per-op f32 numpy reference).
#define FP_BARRIER(x) asm volatile("" : "+v"(x))

// f32 -> bf16 with round-to-nearest-even (bf16 = high 16 bits of f32).
__device__ __forceinline__ uint32_t f2bf_rne(float f) {
  uint32_t u = __float_as_uint(f);
  return (u + 0x7FFFu + ((u >> 16) & 1u)) >> 16;
}

// Fused kernel, block-partitioned:
//   [0, kTiles)        : transpose feat [bn][c][hw] -> featT bf16 [bn*hw][32u32]
//   [kTiles, 2*kTiles) : per-(bn, hw-tile) softmax stats IN-BLOCK + voxel bin
//                        (proven barriered per-op f32) + row-CSR fill.
__global__ void __launch_bounds__(512) lss_fused(
    const float* __restrict__ feat, uint32_t* __restrict__ featT,
    const float* __restrict__ logits, const float* __restrict__ geom,
    unsigned* __restrict__ cnt, uint2* __restrict__ list,
    unsigned* __restrict__ ovf_cnt, uint4* __restrict__ ovf) {
  int blk = blockIdx.x;
  int tid = threadIdx.x;
  if (blk < kTiles) {
    // ---- transpose + bf16 pack ----
    __shared__ float t[64][65];
    int bn = blk / 44, hw0 = (blk % 44) * 64;
    const float* src = feat + (size_t)bn * kC * kHW;
    for (int idx = tid; idx < 64 * 64; idx += 512) {
      int c = idx >> 6, hw = idx & 63;           // consecutive tid -> hw
      t[hw][c] = src[(size_t)c * kHW + hw0 + hw];
    }
    __syncthreads();
    uint32_t* dst = featT + ((size_t)bn * kHW + hw0) * 32;
    for (int idx = tid; idx < 64 * 32; idx += 512) {
      int hw = idx >> 5, j = idx & 31;           // consecutive tid -> j
      uint32_t lo = f2bf_rne(t[hw][2 * j]);
      uint32_t hi = f2bf_rne(t[hw][2 * j + 1]);
      dst[(size_t)hw * 32 + j] = lo | (hi << 16);
    }
  } else {
    // ---- stats + bin + fill: tile (bn, hw0..hw0+63) x all d ----
    __shared__ unsigned shist[kRows4];   // 6.4K
    __shared__ unsigned sbase[kRows4];   // 6.4K
    __shared__ float smax[8 * 64];       // 2K
    __shared__ float ssum[8 * 64];       // 2K
    int tb = blk - kTiles;
    int bn = tb / 44, hw0 = (tb % 44) * 64;
    int hwl = tid & 63, dg = tid >> 6;   // 8 d-groups (waves)
    int hw = hw0 + hwl;
    int b = (bn >= kN) ? 1 : 0;
    int col = bn * kHW + hw;
    int d0 = (dg * kD) >> 3, d1 = ((dg + 1) * kD) >> 3;  // 5..6 d's each
    for (int r = tid; r < kRows4; r += 512) shist[r] = 0;
    // softmax stats (fmax exactly associative -> M identical to serial;
    // S differs ~1ulp from group-partial order -> harmless)
    float x[6];
    float m = -INFINITY;
#pragma unroll
    for (int k = 0; k < 6; ++k) {
      int d = d0 + k;
      if (d < d1) {
        x[k] = logits[(size_t)(bn * kD + d) * kHW + hw];
        m = fmaxf(m, x[k]);
      }
    }
    smax[dg * 64 + hwl] = m;
    __syncthreads();                      // also covers shist zeroing
    float M = smax[hwl];
#pragma unroll
    for (int gg = 1; gg < 8; ++gg) M = fmaxf(M, smax[gg * 64 + hwl]);
    float s = 0.0f;
#pragma unroll
    for (int k = 0; k < 6; ++k) {
      int d = d0 + k;
      if (d < d1) { x[k] = expf(x[k] - M); s += x[k]; }
    }
    ssum[dg * 64 + hwl] = s;
    __syncthreads();
    float S = ssum[hwl];
#pragma unroll
    for (int gg = 1; gg < 8; ++gg) S += ssum[gg * 64 + hwl];
    // voxel bin (proven barriered per-op f32) + per-row4 histogram
    int vv[6];
#pragma unroll
    for (int k = 0; k < 6; ++k) {
      vv[k] = -1;
      int d = d0 + k;
      if (d < d1) {
        size_t g = ((size_t)(bn * kD + d) * kHW + hw) * 3;
        float gx = geom[g + 0];
        float gy = geom[g + 1];
        float gz = geom[g + 2];
        float px = __fmul_rn(gx, 100.0f); FP_BARRIER(px);
        float py = __fmul_rn(gy, 100.0f); FP_BARRIER(py);
        float pz = __fmul_rn(gz, 20.0f);  FP_BARRIER(pz);
        float wx = __fsub_rn(px, 50.0f);  FP_BARRIER(wx);
        float wy = __fsub_rn(py, 50.0f);  FP_BARRIER(wy);
        float wz = __fsub_rn(pz, 10.0f);  FP_BARRIER(wz);
        float tx = __fadd_rn(wx, 50.0f);  FP_BARRIER(tx);
        float ty = __fadd_rn(wy, 50.0f);  FP_BARRIER(ty);
        float tz = __fadd_rn(wz, 10.0f);  FP_BARRIER(tz);
        float qx = __fdiv_rn(tx, 0.5f);   FP_BARRIER(qx);
        float qy = __fdiv_rn(ty, 0.5f);   FP_BARRIER(qy);
        float qz = __fdiv_rn(tz, 20.0f);  FP_BARRIER(qz);
        int ix = (int)floorf(qx);
        int iy = (int)floorf(qy);
        int iz = (int)floorf(qz);
        if ((unsigned)ix < (unsigned)kNX && (unsigned)iy < (unsigned)kNX &&
            (unsigned)iz < 1u) {
          vv[k] = (ix << 8) | iy;
          atomicAdd(&shist[((b * kNX + ix) << 2) + iy / 50], 1u);
        }
      }
    }
    __syncthreads();
    for (int r = tid; r < kRows4; r += 512)
      if (shist[r]) sbase[r] = atomicAdd(&cnt[r], shist[r]);
    __syncthreads();
    // scatter entries {iy|col, wgt} into fixed row segments (line-dense)
#pragma unroll
    for (int k = 0; k < 6; ++k) {
      if (vv[k] < 0) continue;
      int ix = vv[k] >> 8, iy = vv[k] & 255;
      int row4 = ((b * kNX + ix) << 2) + iy / 50;
      float wgt = x[k] / S;
      unsigned key = ((unsigned)iy << 16) | (unsigned)col;
      unsigned pos = atomicAdd(&sbase[row4], 1u);  // LDS cursor
      if (pos < (unsigned)kCap4) {
        list[(size_t)row4 * kCap4 + pos] =
            make_uint2(key, __float_as_uint(wgt));
      } else {                                     // never (+8.6 sigma)
        unsigned o = atomicAdd(ovf_cnt, 1u);
        if (o < (unsigned)kOvfCap)
          ovf[o] = make_uint4((unsigned)row4, key, __float_as_uint(wgt), 0u);
      }
    }
  }
}

// Row gather: one 256-thread block per (b, ix, iy-quarter). Counting-sort
// ~866 entries by iy in LDS, each wave owns 13 iy-bins, lanes split 4x16:
// group g loads uint2 (4 bf16 channels) of entry k+g -> one wave-load
// serves 4 entries at 128B each; 2-deep unroll. Butterfly shfl_xor(16,32)
// reduces groups; accT f32 staged in LDS, one coalesced store.
__global__ void __launch_bounds__(256) lss_rowgather(
    const unsigned* __restrict__ cnt, const uint2* __restrict__ list,
    const uint32_t* __restrict__ featT, float* __restrict__ out,
    const unsigned* __restrict__ ovf_cnt, const uint4* __restrict__ ovf) {
  __shared__ uint2 sl[kCap4];           // 8.96 KB sorted entries
  __shared__ float accT[50 * 67];       // 13.4 KB (stride 67: bank-free)
  __shared__ unsigned hist[64];
  __shared__ unsigned off[51];
  __shared__ unsigned curb[50];
  int tid = threadIdx.x;
  int r4 = blockIdx.x;
  int q = r4 & 3;
  int r = r4 >> 2;
  int b = r / kNX, ix = r - (r / kNX) * kNX;
  int iyb = q * 50;
  size_t s0 = (size_t)r4 * kCap4;
  unsigned n = cnt[r4];
  unsigned ns = min(n, (unsigned)kCap4);

  if (tid < 64) hist[tid] = 0;
  __syncthreads();
  for (unsigned k = tid; k < ns; k += 256)
    atomicAdd(&hist[(list[s0 + k].x >> 16) - iyb], 1u);
  __syncthreads();
  unsigned c0 = (tid < 64) ? hist[tid] : 0u;
  for (int o = 1; o < 64; o <<= 1) {    // inclusive scan over 64 bins
    unsigned xx = (tid < 64 && tid >= o) ? hist[tid - o] : 0u;
    __syncthreads();
    if (tid < 64) hist[tid] += xx;
    __syncthreads();
  }
  if (tid < 50) {
    unsigned st = hist[tid] - c0;
    off[tid] = st;
    curb[tid] = st;
  }
  if (tid == 0) off[50] = ns;
  __syncthreads();
  for (unsigned k = tid; k < ns; k += 256) {
    uint2 a = list[s0 + k];
    unsigned pos = atomicAdd(&curb[(a.x >> 16) - iyb], 1u);
    sl[pos] = a;
  }
  __syncthreads();
  // wave wv owns bins [wv*13, ..): 13,13,13,11
  int wv = tid >> 6, lane = tid & 63;
  int g = lane >> 4, sub = lane & 15;
  int ly0 = wv * 13, ly1 = min(ly0 + 13, 50);
  for (int ly = ly0; ly < ly1; ++ly) {
    unsigned k = off[ly], e = off[ly + 1];
    float a0 = 0, a1 = 0, a2 = 0, a3 = 0;
    unsigned kk = k + g;
    for (; kk + 4 < e; kk += 8) {       // 2 rounds in flight
      uint2 ea = sl[kk];
      uint2 eb = sl[kk + 4];
      uint2 fa = ((const uint2*)(featT + ((size_t)(ea.x & 0xFFFFu) << 5)))[sub];
      uint2 fb = ((const uint2*)(featT + ((size_t)(eb.x & 0xFFFFu) << 5)))[sub];
      float wa = __uint_as_float(ea.y), wb = __uint_as_float(eb.y);
      a0 += wa * __uint_as_float(fa.x << 16);
      a1 += wa * __uint_as_float(fa.x & 0xFFFF0000u);
      a2 += wa * __uint_as_float(fa.y << 16);
      a3 += wa * __uint_as_float(fa.y & 0xFFFF0000u);
      a0 += wb * __uint_as_float(fb.x << 16);
      a1 += wb * __uint_as_float(fb.x & 0xFFFF0000u);
      a2 += wb * __uint_as_float(fb.y << 16);
      a3 += wb * __uint_as_float(fb.y & 0xFFFF0000u);
    }
    if (kk < e) {
      uint2 ea = sl[kk];
      uint2 fa = ((const uint2*)(featT + ((size_t)(ea.x & 0xFFFFu) << 5)))[sub];
      float wa = __uint_as_float(ea.y);
      a0 += wa * __uint_as_float(fa.x << 16);
      a1 += wa * __uint_as_float(fa.x & 0xFFFF0000u);
      a2 += wa * __uint_as_float(fa.y << 16);
      a3 += wa * __uint_as_float(fa.y & 0xFFFF0000u);
    }
    a0 += __shfl_xor(a0, 16); a0 += __shfl_xor(a0, 32);
    a1 += __shfl_xor(a1, 16); a1 += __shfl_xor(a1, 32);
    a2 += __shfl_xor(a2, 16); a2 += __shfl_xor(a2, 32);
    a3 += __shfl_xor(a3, 16); a3 += __shfl_xor(a3, 32);
    if (g == 0) {
      float* dst = &accT[ly * 67 + (sub << 2)];
      dst[0] = a0; dst[1] = a1; dst[2] = a2; dst[3] = a3;
    }
  }
  __syncthreads();
  // overflow epilogue (never taken; kept for correctness)
  unsigned ovfn = min(*ovf_cnt, (unsigned)kOvfCap);
  if (ovfn > 0) {
    for (unsigned k = tid; k < ovfn; k += 256) {
      uint4 a = ovf[k];
      if (a.x != (unsigned)r4) continue;
      int ly = (int)(a.y >> 16) - iyb;
      const uint32_t* fr = featT + ((size_t)(a.y & 0xFFFFu) << 5);
      float w = __uint_as_float(a.z);
      for (int c = 0; c < kC; ++c) {
        uint32_t u = fr[c >> 1];
        float f = __uint_as_float((c & 1) ? (u & 0xFFFF0000u) : (u << 16));
        atomicAdd(&accT[ly * 67 + c], w * f);
      }
    }
    __syncthreads();
  }
  // coalesced tile store (every cell written -> no output memset)
  float* op = out + (size_t)b * kC * kVox + (size_t)ix * kNX + iyb;
  for (int idx = tid; idx < kC * 50; idx += 256) {
    int c = idx / 50, iy = idx - c * 50;
    op[(size_t)c * kVox + iy] = accT[iy * 67 + c];
  }
}

extern "C" void kernel_launch(void* const* d_in, const int* in_sizes, int n_in,
                              void* d_out, int out_size, void* d_ws,
                              size_t ws_size, hipStream_t stream) {
  const float* feat = (const float*)d_in[0];
  const float* logits = (const float*)d_in[1];
  const float* geom = (const float*)d_in[2];
  float* out = (float*)d_out;

  // Workspace layout (16B-aligned chunks): total ~18.7 MB
  char* w = (char*)d_ws;
  uint2* list = (uint2*)w;         w += (size_t)kRows4 * kCap4 * 8;  // 14.34MB
  uint32_t* featT = (uint32_t*)w;  w += (size_t)kBN * kHW * 32 * 4;  // 4.33MB
  uint4* ovf = (uint4*)w;          w += (size_t)kOvfCap * 16;        // 64KB
  unsigned* cnt = (unsigned*)w;    w += (size_t)kRows4 * 4;
  unsigned* ovf_cnt = (unsigned*)w;

  // Zero cnt + ovf_cnt in one memset (adjacent).
  hipMemsetAsync(cnt, 0, (size_t)kRows4 * 4 + 4, stream);

  lss_fused<<<kFusedBlks, 512, 0, stream>>>(feat, featT, logits, geom, cnt,
                                            list, ovf_cnt, ovf);
  lss_rowgather<<<kRows4, 256, 0, stream>>>(cnt, list, featT, out, ovf_cnt,
                                            ovf);
}

// Round 16
// 64.941 us; speedup vs baseline: 9.9740x; 1.0334x over previous
//
#include <hip/hip_runtime.h>
#include <math.h>
#include <stdint.h>

namespace {
constexpr int kB = 2, kN = 6, kC = 64, kD = 41, kH = 32, kW = 88;
constexpr int kHW = kH * kW;                  // 2816
constexpr int kBN = kB * kN;                  // 12
constexpr int kNX = 200;
constexpr int kVox = kNX * kNX;               // 40000
constexpr int kPts = kBN * kD * kHW;          // 1,385,472
constexpr int kRows4 = kB * kNX * 4;          // 1600 rows (b, ix, iy-quarter)
constexpr int kCap4 = 1120;                   // mean 866, +8.6 sigma
constexpr int kOvfCap = 4096;                 // overflow list (never used)

constexpr int kTiles = kBN * (kHW / 64);      // 528 (bn, hw-tile-64)
constexpr int kFusedBlks = kTiles * 2;        // [0,528) transpose | [528,1056) binfill
}  // namespace

// Blocks fp-contraction (hipcc -ffp-contract=fast would fuse mul+sub into
// fma and change voxel binning vs the per-op f32 numpy reference).
#define FP_BARRIER(x) asm volatile("" : "+v"(x))

// f32 -> bf16 with round-to-nearest-even (bf16 = high 16 bits of f32).
__device__ __forceinline__ uint32_t f2bf_rne(float f) {
  uint32_t u = __float_as_uint(f);
  return (u + 0x7FFFu + ((u >> 16) & 1u)) >> 16;
}

// Zero cnt[kRows4] + ovf_cnt. Replaces hipMemsetAsync: rocclr's
// fillBufferAligned dispatch cost ~43us/call (R15 rocprof, #1 dispatch!)
// for 6.4KB. One 256-thread block, ~2us.
__global__ void __launch_bounds__(256) lss_zero(unsigned* __restrict__ cnt) {
  for (int i = threadIdx.x; i <= kRows4; i += 256) cnt[i] = 0u;
}

// Fused kernel, block-partitioned:
//   [0, kTiles)        : transpose feat [bn][c][hw] -> featT bf16 [bn*hw][32u32]
//   [kTiles, 2*kTiles) : per-(bn, hw-tile) softmax stats IN-BLOCK + voxel bin
//                        (proven barriered per-op f32) + row-CSR fill.
__global__ void __launch_bounds__(512) lss_fused(
    const float* __restrict__ feat, uint32_t* __restrict__ featT,
    const float* __restrict__ logits, const float* __restrict__ geom,
    unsigned* __restrict__ cnt, uint2* __restrict__ list,
    unsigned* __restrict__ ovf_cnt, uint4* __restrict__ ovf) {
  int blk = blockIdx.x;
  int tid = threadIdx.x;
  if (blk < kTiles) {
    // ---- transpose + bf16 pack ----
    __shared__ float t[64][65];
    int bn = blk / 44, hw0 = (blk % 44) * 64;
    const float* src = feat + (size_t)bn * kC * kHW;
    for (int idx = tid; idx < 64 * 64; idx += 512) {
      int c = idx >> 6, hw = idx & 63;           // consecutive tid -> hw
      t[hw][c] = src[(size_t)c * kHW + hw0 + hw];
    }
    __syncthreads();
    uint32_t* dst = featT + ((size_t)bn * kHW + hw0) * 32;
    for (int idx = tid; idx < 64 * 32; idx += 512) {
      int hw = idx >> 5, j = idx & 31;           // consecutive tid -> j
      uint32_t lo = f2bf_rne(t[hw][2 * j]);
      uint32_t hi = f2bf_rne(t[hw][2 * j + 1]);
      dst[(size_t)hw * 32 + j] = lo | (hi << 16);
    }
  } else {
    // ---- stats + bin + fill: tile (bn, hw0..hw0+63) x all d ----
    __shared__ unsigned shist[kRows4];   // 6.4K
    __shared__ unsigned sbase[kRows4];   // 6.4K
    __shared__ float smax[8 * 64];       // 2K
    __shared__ float ssum[8 * 64];       // 2K
    int tb = blk - kTiles;
    int bn = tb / 44, hw0 = (tb % 44) * 64;
    int hwl = tid & 63, dg = tid >> 6;   // 8 d-groups (waves)
    int hw = hw0 + hwl;
    int b = (bn >= kN) ? 1 : 0;
    int col = bn * kHW + hw;
    int d0 = (dg * kD) >> 3, d1 = ((dg + 1) * kD) >> 3;  // 5..6 d's each
    for (int r = tid; r < kRows4; r += 512) shist[r] = 0;
    // softmax stats (fmax exactly associative -> M identical to serial;
    // S differs ~1ulp from group-partial order -> harmless)
    float x[6];
    float m = -INFINITY;
#pragma unroll
    for (int k = 0; k < 6; ++k) {
      int d = d0 + k;
      if (d < d1) {
        x[k] = logits[(size_t)(bn * kD + d) * kHW + hw];
        m = fmaxf(m, x[k]);
      }
    }
    smax[dg * 64 + hwl] = m;
    __syncthreads();                      // also covers shist zeroing
    float M = smax[hwl];
#pragma unroll
    for (int gg = 1; gg < 8; ++gg) M = fmaxf(M, smax[gg * 64 + hwl]);
    float s = 0.0f;
#pragma unroll
    for (int k = 0; k < 6; ++k) {
      int d = d0 + k;
      if (d < d1) { x[k] = expf(x[k] - M); s += x[k]; }
    }
    ssum[dg * 64 + hwl] = s;
    __syncthreads();
    float S = ssum[hwl];
#pragma unroll
    for (int gg = 1; gg < 8; ++gg) S += ssum[gg * 64 + hwl];
    // voxel bin (proven barriered per-op f32) + per-row4 histogram
    int vv[6];
#pragma unroll
    for (int k = 0; k < 6; ++k) {
      vv[k] = -1;
      int d = d0 + k;
      if (d < d1) {
        size_t g = ((size_t)(bn * kD + d) * kHW + hw) * 3;
        float gx = geom[g + 0];
        float gy = geom[g + 1];
        float gz = geom[g + 2];
        float px = __fmul_rn(gx, 100.0f); FP_BARRIER(px);
        float py = __fmul_rn(gy, 100.0f); FP_BARRIER(py);
        float pz = __fmul_rn(gz, 20.0f);  FP_BARRIER(pz);
        float wx = __fsub_rn(px, 50.0f);  FP_BARRIER(wx);
        float wy = __fsub_rn(py, 50.0f);  FP_BARRIER(wy);
        float wz = __fsub_rn(pz, 10.0f);  FP_BARRIER(wz);
        float tx = __fadd_rn(wx, 50.0f);  FP_BARRIER(tx);
        float ty = __fadd_rn(wy, 50.0f);  FP_BARRIER(ty);
        float tz = __fadd_rn(wz, 10.0f);  FP_BARRIER(tz);
        float qx = __fdiv_rn(tx, 0.5f);   FP_BARRIER(qx);
        float qy = __fdiv_rn(ty, 0.5f);   FP_BARRIER(qy);
        float qz = __fdiv_rn(tz, 20.0f);  FP_BARRIER(qz);
        int ix = (int)floorf(qx);
        int iy = (int)floorf(qy);
        int iz = (int)floorf(qz);
        if ((unsigned)ix < (unsigned)kNX && (unsigned)iy < (unsigned)kNX &&
            (unsigned)iz < 1u) {
          vv[k] = (ix << 8) | iy;
          atomicAdd(&shist[((b * kNX + ix) << 2) + iy / 50], 1u);
        }
      }
    }
    __syncthreads();
    for (int r = tid; r < kRows4; r += 512)
      if (shist[r]) sbase[r] = atomicAdd(&cnt[r], shist[r]);
    __syncthreads();
    // scatter entries {iy|col, wgt} into fixed row segments (line-dense)
#pragma unroll
    for (int k = 0; k < 6; ++k) {
      if (vv[k] < 0) continue;
      int ix = vv[k] >> 8, iy = vv[k] & 255;
      int row4 = ((b * kNX + ix) << 2) + iy / 50;
      float wgt = x[k] / S;
      unsigned key = ((unsigned)iy << 16) | (unsigned)col;
      unsigned pos = atomicAdd(&sbase[row4], 1u);  // LDS cursor
      if (pos < (unsigned)kCap4) {
        list[(size_t)row4 * kCap4 + pos] =
            make_uint2(key, __float_as_uint(wgt));
      } else {                                     // never (+8.6 sigma)
        unsigned o = atomicAdd(ovf_cnt, 1u);
        if (o < (unsigned)kOvfCap)
          ovf[o] = make_uint4((unsigned)row4, key, __float_as_uint(wgt), 0u);
      }
    }
  }
}

// Row gather: one 256-thread block per (b, ix, iy-quarter). Counting-sort
// ~866 entries by iy in LDS, each wave owns 13 iy-bins, lanes split 4x16:
// group g loads uint2 (4 bf16 channels) of entry k+g -> one wave-load
// serves 4 entries at 128B each; 2-deep unroll. Butterfly shfl_xor(16,32)
// reduces groups; accT f32 staged in LDS, one coalesced store.
__global__ void __launch_bounds__(256) lss_rowgather(
    const unsigned* __restrict__ cnt, const uint2* __restrict__ list,
    const uint32_t* __restrict__ featT, float* __restrict__ out,
    const unsigned* __restrict__ ovf_cnt, const uint4* __restrict__ ovf) {
  __shared__ uint2 sl[kCap4];           // 8.96 KB sorted entries
  __shared__ float accT[50 * 67];       // 13.4 KB (stride 67: bank-free)
  __shared__ unsigned hist[64];
  __shared__ unsigned off[51];
  __shared__ unsigned curb[50];
  int tid = threadIdx.x;
  int r4 = blockIdx.x;
  int q = r4 & 3;
  int r = r4 >> 2;
  int b = r / kNX, ix = r - (r / kNX) * kNX;
  int iyb = q * 50;
  size_t s0 = (size_t)r4 * kCap4;
  unsigned n = cnt[r4];
  unsigned ns = min(n, (unsigned)kCap4);

  if (tid < 64) hist[tid] = 0;
  __syncthreads();
  for (unsigned k = tid; k < ns; k += 256)
    atomicAdd(&hist[(list[s0 + k].x >> 16) - iyb], 1u);
  __syncthreads();
  unsigned c0 = (tid < 64) ? hist[tid] : 0u;
  for (int o = 1; o < 64; o <<= 1) {    // inclusive scan over 64 bins
    unsigned xx = (tid < 64 && tid >= o) ? hist[tid - o] : 0u;
    __syncthreads();
    if (tid < 64) hist[tid] += xx;
    __syncthreads();
  }
  if (tid < 50) {
    unsigned st = hist[tid] - c0;
    off[tid] = st;
    curb[tid] = st;
  }
  if (tid == 0) off[50] = ns;
  __syncthreads();
  for (unsigned k = tid; k < ns; k += 256) {
    uint2 a = list[s0 + k];
    unsigned pos = atomicAdd(&curb[(a.x >> 16) - iyb], 1u);
    sl[pos] = a;
  }
  __syncthreads();
  // wave wv owns bins [wv*13, ..): 13,13,13,11
  int wv = tid >> 6, lane = tid & 63;
  int g = lane >> 4, sub = lane & 15;
  int ly0 = wv * 13, ly1 = min(ly0 + 13, 50);
  for (int ly = ly0; ly < ly1; ++ly) {
    unsigned k = off[ly], e = off[ly + 1];
    float a0 = 0, a1 = 0, a2 = 0, a3 = 0;
    unsigned kk = k + g;
    for (; kk + 4 < e; kk += 8) {       // 2 rounds in flight
      uint2 ea = sl[kk];
      uint2 eb = sl[kk + 4];
      uint2 fa = ((const uint2*)(featT + ((size_t)(ea.x & 0xFFFFu) << 5)))[sub];
      uint2 fb = ((const uint2*)(featT + ((size_t)(eb.x & 0xFFFFu) << 5)))[sub];
      float wa = __uint_as_float(ea.y), wb = __uint_as_float(eb.y);
      a0 += wa * __uint_as_float(fa.x << 16);
      a1 += wa * __uint_as_float(fa.x & 0xFFFF0000u);
      a2 += wa * __uint_as_float(fa.y << 16);
      a3 += wa * __uint_as_float(fa.y & 0xFFFF0000u);
      a0 += wb * __uint_as_float(fb.x << 16);
      a1 += wb * __uint_as_float(fb.x & 0xFFFF0000u);
      a2 += wb * __uint_as_float(fb.y << 16);
      a3 += wb * __uint_as_float(fb.y & 0xFFFF0000u);
    }
    if (kk < e) {
      uint2 ea = sl[kk];
      uint2 fa = ((const uint2*)(featT + ((size_t)(ea.x & 0xFFFFu) << 5)))[sub];
      float wa = __uint_as_float(ea.y);
      a0 += wa * __uint_as_float(fa.x << 16);
      a1 += wa * __uint_as_float(fa.x & 0xFFFF0000u);
      a2 += wa * __uint_as_float(fa.y << 16);
      a3 += wa * __uint_as_float(fa.y & 0xFFFF0000u);
    }
    a0 += __shfl_xor(a0, 16); a0 += __shfl_xor(a0, 32);
    a1 += __shfl_xor(a1, 16); a1 += __shfl_xor(a1, 32);
    a2 += __shfl_xor(a2, 16); a2 += __shfl_xor(a2, 32);
    a3 += __shfl_xor(a3, 16); a3 += __shfl_xor(a3, 32);
    if (g == 0) {
      float* dst = &accT[ly * 67 + (sub << 2)];
      dst[0] = a0; dst[1] = a1; dst[2] = a2; dst[3] = a3;
    }
  }
  __syncthreads();
  // overflow epilogue (never taken; kept for correctness)
  unsigned ovfn = min(*ovf_cnt, (unsigned)kOvfCap);
  if (ovfn > 0) {
    for (unsigned k = tid; k < ovfn; k += 256) {
      uint4 a = ovf[k];
      if (a.x != (unsigned)r4) continue;
      int ly = (int)(a.y >> 16) - iyb;
      const uint32_t* fr = featT + ((size_t)(a.y & 0xFFFFu) << 5);
      float w = __uint_as_float(a.z);
      for (int c = 0; c < kC; ++c) {
        uint32_t u = fr[c >> 1];
        float f = __uint_as_float((c & 1) ? (u & 0xFFFF0000u) : (u << 16));
        atomicAdd(&accT[ly * 67 + c], w * f);
      }
    }
    __syncthreads();
  }
  // coalesced tile store (every cell written -> no output memset)
  float* op = out + (size_t)b * kC * kVox + (size_t)ix * kNX + iyb;
  for (int idx = tid; idx < kC * 50; idx += 256) {
    int c = idx / 50, iy = idx - c * 50;
    op[(size_t)c * kVox + iy] = accT[iy * 67 + c];
  }
}

extern "C" void kernel_launch(void* const* d_in, const int* in_sizes, int n_in,
                              void* d_out, int out_size, void* d_ws,
                              size_t ws_size, hipStream_t stream) {
  const float* feat = (const float*)d_in[0];
  const float* logits = (const float*)d_in[1];
  const float* geom = (const float*)d_in[2];
  float* out = (float*)d_out;

  // Workspace layout (16B-aligned chunks): total ~18.7 MB
  char* w = (char*)d_ws;
  uint2* list = (uint2*)w;         w += (size_t)kRows4 * kCap4 * 8;  // 14.34MB
  uint32_t* featT = (uint32_t*)w;  w += (size_t)kBN * kHW * 32 * 4;  // 4.33MB
  uint4* ovf = (uint4*)w;          w += (size_t)kOvfCap * 16;        // 64KB
  unsigned* cnt = (unsigned*)w;    w += (size_t)kRows4 * 4;
  // ovf_cnt = cnt[kRows4] (zeroed together by lss_zero)
  unsigned* ovf_cnt = cnt + kRows4;

  lss_zero<<<1, 256, 0, stream>>>(cnt);
  lss_fused<<<kFusedBlks, 512, 0, stream>>>(feat, featT, logits, geom, cnt,
                                            list, ovf_cnt, ovf);
  lss_rowgather<<<kRows4, 256, 0, stream>>>(cnt, list, featT, out, ovf_cnt,
                                            ovf);
}

// Round 17
// 56.195 us; speedup vs baseline: 11.5263x; 1.1556x over previous
//
#include <hip/hip_runtime.h>
#include <math.h>
#include <stdint.h>

namespace {
constexpr int kB = 2, kN = 6, kC = 64, kD = 41, kH = 32, kW = 88;
constexpr int kHW = kH * kW;                  // 2816
constexpr int kBN = kB * kN;                  // 12
constexpr int kNX = 200;
constexpr int kVox = kNX * kNX;               // 40000
constexpr int kPts = kBN * kD * kHW;          // 1,385,472
constexpr int kRows4 = kB * kNX * 4;          // 1600 rows (b, ix, iy-quarter)
constexpr int kCap4 = 1120;                   // mean 866, +8.6 sigma
constexpr int kOvfCap = 4096;                 // overflow list (never used)

constexpr int kTiles = kBN * (kHW / 64);      // 528 (bn, hw-tile-64)
constexpr int kFusedBlks = kTiles * 2;        // [0,528) transpose | [528,1056) binfill
}  // namespace

// Blocks fp-contraction (hipcc -ffp-contract=fast would fuse mul+sub into
// fma and change voxel binning vs the per-op f32 numpy reference).
#define FP_BARRIER(x) asm volatile("" : "+v"(x))

// f32 -> bf16 with round-to-nearest-even (bf16 = high 16 bits of f32).
__device__ __forceinline__ uint32_t f2bf_rne(float f) {
  uint32_t u = __float_as_uint(f);
  return (u + 0x7FFFu + ((u >> 16) & 1u)) >> 16;
}

// Zero cnt[kRows4] + ovf_cnt (6.4KB). ~2us in the timed graph.
__global__ void __launch_bounds__(256) lss_zero(unsigned* __restrict__ cnt) {
  for (int i = threadIdx.x; i <= kRows4; i += 256) cnt[i] = 0u;
}

// Fused kernel, block-partitioned (identical to R16 passing version):
//   [0, kTiles)        : transpose feat [bn][c][hw] -> featT bf16 [bn*hw][32u32]
//   [kTiles, 2*kTiles) : per-(bn, hw-tile) softmax stats IN-BLOCK + voxel bin
//                        (proven barriered per-op f32) + row-CSR fill.
__global__ void __launch_bounds__(512) lss_fused(
    const float* __restrict__ feat, uint32_t* __restrict__ featT,
    const float* __restrict__ logits, const float* __restrict__ geom,
    unsigned* __restrict__ cnt, uint2* __restrict__ list,
    unsigned* __restrict__ ovf_cnt, uint4* __restrict__ ovf) {
  int blk = blockIdx.x;
  int tid = threadIdx.x;
  if (blk < kTiles) {
    // ---- transpose + bf16 pack ----
    __shared__ float t[64][65];
    int bn = blk / 44, hw0 = (blk % 44) * 64;
    const float* src = feat + (size_t)bn * kC * kHW;
    for (int idx = tid; idx < 64 * 64; idx += 512) {
      int c = idx >> 6, hw = idx & 63;           // consecutive tid -> hw
      t[hw][c] = src[(size_t)c * kHW + hw0 + hw];
    }
    __syncthreads();
    uint32_t* dst = featT + ((size_t)bn * kHW + hw0) * 32;
    for (int idx = tid; idx < 64 * 32; idx += 512) {
      int hw = idx >> 5, j = idx & 31;           // consecutive tid -> j
      uint32_t lo = f2bf_rne(t[hw][2 * j]);
      uint32_t hi = f2bf_rne(t[hw][2 * j + 1]);
      dst[(size_t)hw * 32 + j] = lo | (hi << 16);
    }
  } else {
    // ---- stats + bin + fill: tile (bn, hw0..hw0+63) x all d ----
    __shared__ unsigned shist[kRows4];   // 6.4K
    __shared__ unsigned sbase[kRows4];   // 6.4K
    __shared__ float smax[8 * 64];       // 2K
    __shared__ float ssum[8 * 64];       // 2K
    int tb = blk - kTiles;
    int bn = tb / 44, hw0 = (tb % 44) * 64;
    int hwl = tid & 63, dg = tid >> 6;   // 8 d-groups (waves)
    int hw = hw0 + hwl;
    int b = (bn >= kN) ? 1 : 0;
    int col = bn * kHW + hw;
    int d0 = (dg * kD) >> 3, d1 = ((dg + 1) * kD) >> 3;  // 5..6 d's each
    for (int r = tid; r < kRows4; r += 512) shist[r] = 0;
    // softmax stats (fmax exactly associative -> M identical to serial;
    // S differs ~1ulp from group-partial order -> harmless)
    float x[6];
    float m = -INFINITY;
#pragma unroll
    for (int k = 0; k < 6; ++k) {
      int d = d0 + k;
      if (d < d1) {
        x[k] = logits[(size_t)(bn * kD + d) * kHW + hw];
        m = fmaxf(m, x[k]);
      }
    }
    smax[dg * 64 + hwl] = m;
    __syncthreads();                      // also covers shist zeroing
    float M = smax[hwl];
#pragma unroll
    for (int gg = 1; gg < 8; ++gg) M = fmaxf(M, smax[gg * 64 + hwl]);
    float s = 0.0f;
#pragma unroll
    for (int k = 0; k < 6; ++k) {
      int d = d0 + k;
      if (d < d1) { x[k] = expf(x[k] - M); s += x[k]; }
    }
    ssum[dg * 64 + hwl] = s;
    __syncthreads();
    float S = ssum[hwl];
#pragma unroll
    for (int gg = 1; gg < 8; ++gg) S += ssum[gg * 64 + hwl];
    // voxel bin (proven barriered per-op f32) + per-row4 histogram
    int vv[6];
#pragma unroll
    for (int k = 0; k < 6; ++k) {
      vv[k] = -1;
      int d = d0 + k;
      if (d < d1) {
        size_t g = ((size_t)(bn * kD + d) * kHW + hw) * 3;
        float gx = geom[g + 0];
        float gy = geom[g + 1];
        float gz = geom[g + 2];
        float px = __fmul_rn(gx, 100.0f); FP_BARRIER(px);
        float py = __fmul_rn(gy, 100.0f); FP_BARRIER(py);
        float pz = __fmul_rn(gz, 20.0f);  FP_BARRIER(pz);
        float wx = __fsub_rn(px, 50.0f);  FP_BARRIER(wx);
        float wy = __fsub_rn(py, 50.0f);  FP_BARRIER(wy);
        float wz = __fsub_rn(pz, 10.0f);  FP_BARRIER(wz);
        float tx = __fadd_rn(wx, 50.0f);  FP_BARRIER(tx);
        float ty = __fadd_rn(wy, 50.0f);  FP_BARRIER(ty);
        float tz = __fadd_rn(wz, 10.0f);  FP_BARRIER(tz);
        float qx = __fdiv_rn(tx, 0.5f);   FP_BARRIER(qx);
        float qy = __fdiv_rn(ty, 0.5f);   FP_BARRIER(qy);
        float qz = __fdiv_rn(tz, 20.0f);  FP_BARRIER(qz);
        int ix = (int)floorf(qx);
        int iy = (int)floorf(qy);
        int iz = (int)floorf(qz);
        if ((unsigned)ix < (unsigned)kNX && (unsigned)iy < (unsigned)kNX &&
            (unsigned)iz < 1u) {
          vv[k] = (ix << 8) | iy;
          atomicAdd(&shist[((b * kNX + ix) << 2) + iy / 50], 1u);
        }
      }
    }
    __syncthreads();
    for (int r = tid; r < kRows4; r += 512)
      if (shist[r]) sbase[r] = atomicAdd(&cnt[r], shist[r]);
    __syncthreads();
    // scatter entries {iy|col, wgt} into fixed row segments (line-dense)
#pragma unroll
    for (int k = 0; k < 6; ++k) {
      if (vv[k] < 0) continue;
      int ix = vv[k] >> 8, iy = vv[k] & 255;
      int row4 = ((b * kNX + ix) << 2) + iy / 50;
      float wgt = x[k] / S;
      unsigned key = ((unsigned)iy << 16) | (unsigned)col;
      unsigned pos = atomicAdd(&sbase[row4], 1u);  // LDS cursor
      if (pos < (unsigned)kCap4) {
        list[(size_t)row4 * kCap4 + pos] =
            make_uint2(key, __float_as_uint(wgt));
      } else {                                     // never (+8.6 sigma)
        unsigned o = atomicAdd(ovf_cnt, 1u);
        if (o < (unsigned)kOvfCap)
          ovf[o] = make_uint4((unsigned)row4, key, __float_as_uint(wgt), 0u);
      }
    }
  }
}

// Row gather v4: 512 threads per (b, ix, iy-quarter). Counting-sort ~866
// entries by iy in LDS, then ONE 8-lane group PER BIN (ly = tid>>3, 50
// active groups): lane sub loads uint4 (8 bf16 channels) of each entry,
// 4-deep unrolled -> 4 outstanding 128B lines per lane (MLP fix vs R16's
// 2). No shuffles: lane sub owns channels sub*8..+7, writes accT[ly][..]
// directly. One coalesced tile store; every cell written -> no memset.
__global__ void __launch_bounds__(512) lss_rowgather(
    const unsigned* __restrict__ cnt, const uint2* __restrict__ list,
    const uint32_t* __restrict__ featT, float* __restrict__ out,
    const unsigned* __restrict__ ovf_cnt, const uint4* __restrict__ ovf) {
  __shared__ uint2 sl[kCap4];           // 8.96 KB sorted entries
  __shared__ float accT[50 * 65];       // 13.0 KB (pad 65: store bank-free)
  __shared__ unsigned hist[64];
  __shared__ unsigned off[51];
  __shared__ unsigned curb[50];
  int tid = threadIdx.x;
  int r4 = blockIdx.x;
  int q = r4 & 3;
  int r = r4 >> 2;
  int b = r / kNX, ix = r - (r / kNX) * kNX;
  int iyb = q * 50;
  size_t s0 = (size_t)r4 * kCap4;
  unsigned n = cnt[r4];
  unsigned ns = min(n, (unsigned)kCap4);

  if (tid < 64) hist[tid] = 0;
  __syncthreads();
  for (unsigned k = tid; k < ns; k += 512)
    atomicAdd(&hist[(list[s0 + k].x >> 16) - iyb], 1u);
  __syncthreads();
  unsigned c0 = (tid < 64) ? hist[tid] : 0u;
  for (int o = 1; o < 64; o <<= 1) {    // inclusive scan over 64 bins
    unsigned xx = (tid < 64 && tid >= o) ? hist[tid - o] : 0u;
    __syncthreads();
    if (tid < 64) hist[tid] += xx;
    __syncthreads();
  }
  if (tid < 50) {
    unsigned st = hist[tid] - c0;
    off[tid] = st;
    curb[tid] = st;
  }
  if (tid == 0) off[50] = ns;
  __syncthreads();
  for (unsigned k = tid; k < ns; k += 512) {
    uint2 a = list[s0 + k];
    unsigned pos = atomicAdd(&curb[(a.x >> 16) - iyb], 1u);
    sl[pos] = a;
  }
  __syncthreads();
  // accumulate: group ly = tid>>3 owns bin ly; lane sub = tid&7 owns
  // channels sub*8..sub*8+7 (uint4 = 4 u32 = 8 bf16)
  int ly = tid >> 3, sub = tid & 7;
  if (ly < 50) {
    unsigned k = off[ly], e = off[ly + 1];
    float a0 = 0, a1 = 0, a2 = 0, a3 = 0, a4 = 0, a5 = 0, a6 = 0, a7 = 0;
    for (; k + 4 <= e; k += 4) {        // 4 entries -> 4 lines in flight
      uint2 e0 = sl[k + 0];
      uint2 e1 = sl[k + 1];
      uint2 e2 = sl[k + 2];
      uint2 e3 = sl[k + 3];
      uint4 f0 = ((const uint4*)(featT + ((size_t)(e0.x & 0xFFFFu) << 5)))[sub];
      uint4 f1 = ((const uint4*)(featT + ((size_t)(e1.x & 0xFFFFu) << 5)))[sub];
      uint4 f2 = ((const uint4*)(featT + ((size_t)(e2.x & 0xFFFFu) << 5)))[sub];
      uint4 f3 = ((const uint4*)(featT + ((size_t)(e3.x & 0xFFFFu) << 5)))[sub];
      float w0 = __uint_as_float(e0.y), w1 = __uint_as_float(e1.y);
      float w2 = __uint_as_float(e2.y), w3 = __uint_as_float(e3.y);
      a0 += w0 * __uint_as_float(f0.x << 16);
      a1 += w0 * __uint_as_float(f0.x & 0xFFFF0000u);
      a2 += w0 * __uint_as_float(f0.y << 16);
      a3 += w0 * __uint_as_float(f0.y & 0xFFFF0000u);
      a4 += w0 * __uint_as_float(f0.z << 16);
      a5 += w0 * __uint_as_float(f0.z & 0xFFFF0000u);
      a6 += w0 * __uint_as_float(f0.w << 16);
      a7 += w0 * __uint_as_float(f0.w & 0xFFFF0000u);
      a0 += w1 * __uint_as_float(f1.x << 16);
      a1 += w1 * __uint_as_float(f1.x & 0xFFFF0000u);
      a2 += w1 * __uint_as_float(f1.y << 16);
      a3 += w1 * __uint_as_float(f1.y & 0xFFFF0000u);
      a4 += w1 * __uint_as_float(f1.z << 16);
      a5 += w1 * __uint_as_float(f1.z & 0xFFFF0000u);
      a6 += w1 * __uint_as_float(f1.w << 16);
      a7 += w1 * __uint_as_float(f1.w & 0xFFFF0000u);
      a0 += w2 * __uint_as_float(f2.x << 16);
      a1 += w2 * __uint_as_float(f2.x & 0xFFFF0000u);
      a2 += w2 * __uint_as_float(f2.y << 16);
      a3 += w2 * __uint_as_float(f2.y & 0xFFFF0000u);
      a4 += w2 * __uint_as_float(f2.z << 16);
      a5 += w2 * __uint_as_float(f2.z & 0xFFFF0000u);
      a6 += w2 * __uint_as_float(f2.w << 16);
      a7 += w2 * __uint_as_float(f2.w & 0xFFFF0000u);
      a0 += w3 * __uint_as_float(f3.x << 16);
      a1 += w3 * __uint_as_float(f3.x & 0xFFFF0000u);
      a2 += w3 * __uint_as_float(f3.y << 16);
      a3 += w3 * __uint_as_float(f3.y & 0xFFFF0000u);
      a4 += w3 * __uint_as_float(f3.z << 16);
      a5 += w3 * __uint_as_float(f3.z & 0xFFFF0000u);
      a6 += w3 * __uint_as_float(f3.w << 16);
      a7 += w3 * __uint_as_float(f3.w & 0xFFFF0000u);
    }
    for (; k < e; ++k) {
      uint2 ea = sl[k];
      uint4 fa = ((const uint4*)(featT + ((size_t)(ea.x & 0xFFFFu) << 5)))[sub];
      float wa = __uint_as_float(ea.y);
      a0 += wa * __uint_as_float(fa.x << 16);
      a1 += wa * __uint_as_float(fa.x & 0xFFFF0000u);
      a2 += wa * __uint_as_float(fa.y << 16);
      a3 += wa * __uint_as_float(fa.y & 0xFFFF0000u);
      a4 += wa * __uint_as_float(fa.z << 16);
      a5 += wa * __uint_as_float(fa.z & 0xFFFF0000u);
      a6 += wa * __uint_as_float(fa.w << 16);
      a7 += wa * __uint_as_float(fa.w & 0xFFFF0000u);
    }
    float* dst = &accT[ly * 65 + (sub << 3)];
    dst[0] = a0; dst[1] = a1; dst[2] = a2; dst[3] = a3;
    dst[4] = a4; dst[5] = a5; dst[6] = a6; dst[7] = a7;
  }
  __syncthreads();
  // overflow epilogue (never taken; kept for correctness)
  unsigned ovfn = min(*ovf_cnt, (unsigned)kOvfCap);
  if (ovfn > 0) {
    for (unsigned k = tid; k < ovfn; k += 512) {
      uint4 a = ovf[k];
      if (a.x != (unsigned)r4) continue;
      int lyo = (int)(a.y >> 16) - iyb;
      const uint32_t* fr = featT + ((size_t)(a.y & 0xFFFFu) << 5);
      float w = __uint_as_float(a.z);
      for (int c = 0; c < kC; ++c) {
        uint32_t u = fr[c >> 1];
        float f = __uint_as_float((c & 1) ? (u & 0xFFFF0000u) : (u << 16));
        atomicAdd(&accT[lyo * 65 + c], w * f);
      }
    }
    __syncthreads();
  }
  // coalesced tile store (every cell written -> no output memset)
  float* op = out + (size_t)b * kC * kVox + (size_t)ix * kNX + iyb;
  for (int idx = tid; idx < kC * 50; idx += 512) {
    int c = idx / 50, iy = idx - c * 50;
    op[(size_t)c * kVox + iy] = accT[iy * 65 + c];
  }
}

extern "C" void kernel_launch(void* const* d_in, const int* in_sizes, int n_in,
                              void* d_out, int out_size, void* d_ws,
                              size_t ws_size, hipStream_t stream) {
  const float* feat = (const float*)d_in[0];
  const float* logits = (const float*)d_in[1];
  const float* geom = (const float*)d_in[2];
  float* out = (float*)d_out;

  // Workspace layout (16B-aligned chunks): total ~18.7 MB
  char* w = (char*)d_ws;
  uint2* list = (uint2*)w;         w += (size_t)kRows4 * kCap4 * 8;  // 14.34MB
  uint32_t* featT = (uint32_t*)w;  w += (size_t)kBN * kHW * 32 * 4;  // 4.33MB
  uint4* ovf = (uint4*)w;          w += (size_t)kOvfCap * 16;        // 64KB
  unsigned* cnt = (unsigned*)w;    w += (size_t)kRows4 * 4;
  // ovf_cnt = cnt[kRows4] (zeroed together by lss_zero)
  unsigned* ovf_cnt = cnt + kRows4;

  lss_zero<<<1, 256, 0, stream>>>(cnt);
  lss_fused<<<kFusedBlks, 512, 0, stream>>>(feat, featT, logits, geom, cnt,
                                            list, ovf_cnt, ovf);
  lss_rowgather<<<kRows4, 512, 0, stream>>>(cnt, list, featT, out, ovf_cnt,
                                            ovf);
}

// Round 18
// 53.617 us; speedup vs baseline: 12.0805x; 1.0481x over previous
//
#include <hip/hip_runtime.h>
#include <math.h>
#include <stdint.h>

namespace {
constexpr int kB = 2, kN = 6, kC = 64, kD = 41, kH = 32, kW = 88;
constexpr int kHW = kH * kW;                  // 2816
constexpr int kBN = kB * kN;                  // 12
constexpr int kNX = 200;
constexpr int kVox = kNX * kNX;               // 40000
constexpr int kPts = kBN * kD * kHW;          // 1,385,472
constexpr int kRows4 = kB * kNX * 4;          // 1600 rows (b, ix, iy-quarter)
constexpr int kCap4 = 1120;                   // mean 866, +8.6 sigma
constexpr int kOvfCap = 4096;                 // overflow list (never used)

constexpr int kTiles = kBN * (kHW / 64);      // 528 (bn, hw-tile-64)
constexpr int kFusedBlks = kTiles * 2;        // [0,528) transpose | [528,1056) binfill
}  // namespace

// Blocks fp-contraction (hipcc -ffp-contract=fast would fuse mul+sub into
// fma and change voxel binning vs the per-op f32 numpy reference).
#define FP_BARRIER(x) asm volatile("" : "+v"(x))

// f32 -> bf16 with round-to-nearest-even (bf16 = high 16 bits of f32).
__device__ __forceinline__ uint32_t f2bf_rne(float f) {
  uint32_t u = __float_as_uint(f);
  return (u + 0x7FFFu + ((u >> 16) & 1u)) >> 16;
}

// Zero cnt[kRows4] + ovf_cnt (6.4KB). ~2us in the timed graph.
__global__ void __launch_bounds__(256) lss_zero(unsigned* __restrict__ cnt) {
  for (int i = threadIdx.x; i <= kRows4; i += 256) cnt[i] = 0u;
}

// Fused kernel, block-partitioned (identical to R17 passing version):
//   [0, kTiles)        : transpose feat [bn][c][hw] -> featT bf16 [bn*hw][32u32]
//   [kTiles, 2*kTiles) : per-(bn, hw-tile) softmax stats IN-BLOCK + voxel bin
//                        (proven barriered per-op f32) + row-CSR fill.
__global__ void __launch_bounds__(512) lss_fused(
    const float* __restrict__ feat, uint32_t* __restrict__ featT,
    const float* __restrict__ logits, const float* __restrict__ geom,
    unsigned* __restrict__ cnt, uint2* __restrict__ list,
    unsigned* __restrict__ ovf_cnt, uint4* __restrict__ ovf) {
  int blk = blockIdx.x;
  int tid = threadIdx.x;
  if (blk < kTiles) {
    // ---- transpose + bf16 pack ----
    __shared__ float t[64][65];
    int bn = blk / 44, hw0 = (blk % 44) * 64;
    const float* src = feat + (size_t)bn * kC * kHW;
    for (int idx = tid; idx < 64 * 64; idx += 512) {
      int c = idx >> 6, hw = idx & 63;           // consecutive tid -> hw
      t[hw][c] = src[(size_t)c * kHW + hw0 + hw];
    }
    __syncthreads();
    uint32_t* dst = featT + ((size_t)bn * kHW + hw0) * 32;
    for (int idx = tid; idx < 64 * 32; idx += 512) {
      int hw = idx >> 5, j = idx & 31;           // consecutive tid -> j
      uint32_t lo = f2bf_rne(t[hw][2 * j]);
      uint32_t hi = f2bf_rne(t[hw][2 * j + 1]);
      dst[(size_t)hw * 32 + j] = lo | (hi << 16);
    }
  } else {
    // ---- stats + bin + fill: tile (bn, hw0..hw0+63) x all d ----
    __shared__ unsigned shist[kRows4];   // 6.4K
    __shared__ unsigned sbase[kRows4];   // 6.4K
    __shared__ float smax[8 * 64];       // 2K
    __shared__ float ssum[8 * 64];       // 2K
    int tb = blk - kTiles;
    int bn = tb / 44, hw0 = (tb % 44) * 64;
    int hwl = tid & 63, dg = tid >> 6;   // 8 d-groups (waves)
    int hw = hw0 + hwl;
    int b = (bn >= kN) ? 1 : 0;
    int col = bn * kHW + hw;
    int d0 = (dg * kD) >> 3, d1 = ((dg + 1) * kD) >> 3;  // 5..6 d's each
    for (int r = tid; r < kRows4; r += 512) shist[r] = 0;
    // softmax stats (fmax exactly associative -> M identical to serial;
    // S differs ~1ulp from group-partial order -> harmless)
    float x[6];
    float m = -INFINITY;
#pragma unroll
    for (int k = 0; k < 6; ++k) {
      int d = d0 + k;
      if (d < d1) {
        x[k] = logits[(size_t)(bn * kD + d) * kHW + hw];
        m = fmaxf(m, x[k]);
      }
    }
    smax[dg * 64 + hwl] = m;
    __syncthreads();                      // also covers shist zeroing
    float M = smax[hwl];
#pragma unroll
    for (int gg = 1; gg < 8; ++gg) M = fmaxf(M, smax[gg * 64 + hwl]);
    float s = 0.0f;
#pragma unroll
    for (int k = 0; k < 6; ++k) {
      int d = d0 + k;
      if (d < d1) { x[k] = expf(x[k] - M); s += x[k]; }
    }
    ssum[dg * 64 + hwl] = s;
    __syncthreads();
    float S = ssum[hwl];
#pragma unroll
    for (int gg = 1; gg < 8; ++gg) S += ssum[gg * 64 + hwl];
    // voxel bin (proven barriered per-op f32) + per-row4 histogram
    int vv[6];
#pragma unroll
    for (int k = 0; k < 6; ++k) {
      vv[k] = -1;
      int d = d0 + k;
      if (d < d1) {
        size_t g = ((size_t)(bn * kD + d) * kHW + hw) * 3;
        float gx = geom[g + 0];
        float gy = geom[g + 1];
        float gz = geom[g + 2];
        float px = __fmul_rn(gx, 100.0f); FP_BARRIER(px);
        float py = __fmul_rn(gy, 100.0f); FP_BARRIER(py);
        float pz = __fmul_rn(gz, 20.0f);  FP_BARRIER(pz);
        float wx = __fsub_rn(px, 50.0f);  FP_BARRIER(wx);
        float wy = __fsub_rn(py, 50.0f);  FP_BARRIER(wy);
        float wz = __fsub_rn(pz, 10.0f);  FP_BARRIER(wz);
        float tx = __fadd_rn(wx, 50.0f);  FP_BARRIER(tx);
        float ty = __fadd_rn(wy, 50.0f);  FP_BARRIER(ty);
        float tz = __fadd_rn(wz, 10.0f);  FP_BARRIER(tz);
        float qx = __fdiv_rn(tx, 0.5f);   FP_BARRIER(qx);
        float qy = __fdiv_rn(ty, 0.5f);   FP_BARRIER(qy);
        float qz = __fdiv_rn(tz, 20.0f);  FP_BARRIER(qz);
        int ix = (int)floorf(qx);
        int iy = (int)floorf(qy);
        int iz = (int)floorf(qz);
        if ((unsigned)ix < (unsigned)kNX && (unsigned)iy < (unsigned)kNX &&
            (unsigned)iz < 1u) {
          vv[k] = (ix << 8) | iy;
          atomicAdd(&shist[((b * kNX + ix) << 2) + iy / 50], 1u);
        }
      }
    }
    __syncthreads();
    for (int r = tid; r < kRows4; r += 512)
      if (shist[r]) sbase[r] = atomicAdd(&cnt[r], shist[r]);
    __syncthreads();
    // scatter entries {iy|col, wgt} into fixed row segments (line-dense)
#pragma unroll
    for (int k = 0; k < 6; ++k) {
      if (vv[k] < 0) continue;
      int ix = vv[k] >> 8, iy = vv[k] & 255;
      int row4 = ((b * kNX + ix) << 2) + iy / 50;
      float wgt = x[k] / S;
      unsigned key = ((unsigned)iy << 16) | (unsigned)col;
      unsigned pos = atomicAdd(&sbase[row4], 1u);  // LDS cursor
      if (pos < (unsigned)kCap4) {
        list[(size_t)row4 * kCap4 + pos] =
            make_uint2(key, __float_as_uint(wgt));
      } else {                                     // never (+8.6 sigma)
        unsigned o = atomicAdd(ovf_cnt, 1u);
        if (o < (unsigned)kOvfCap)
          ovf[o] = make_uint4((unsigned)row4, key, __float_as_uint(wgt), 0u);
      }
    }
  }
}

// Row gather v5: 512 threads per (b, ix, iy-quarter).
// NEW vs R17: (1) XCD-aware blockIdx swizzle — each XCD owns a contiguous
// 200-r4 chunk = one b's featT half (2.16MB) + its list slice (1.79MB)
// ~ 4MB = one XCD L2 -> gather becomes L2-resident (R14 showed 12x HBM
// re-fetch without this). (2) single global pass: pass1 stashes raw
// entries in LDS while histogramming (list read once); 64-bin scan done
// by wave 0 via shfl (no barriers).
__global__ void __launch_bounds__(512) lss_rowgather(
    const unsigned* __restrict__ cnt, const uint2* __restrict__ list,
    const uint32_t* __restrict__ featT, float* __restrict__ out,
    const unsigned* __restrict__ ovf_cnt, const uint4* __restrict__ ovf) {
  __shared__ uint2 slr[kCap4];          // 8.96 KB raw entries (arrival order)
  __shared__ uint2 sl[kCap4];           // 8.96 KB sorted entries
  __shared__ float accT[50 * 65];       // 13.0 KB (pad 65: store bank-free)
  __shared__ unsigned hist[64];
  __shared__ unsigned off[51];
  __shared__ unsigned curb[50];
  int tid = threadIdx.x;
  // XCD swizzle: bijective (kRows4 % 8 == 0); XCD x gets r4 in [x*200,(x+1)*200)
  int r4 = ((blockIdx.x & 7) * (kRows4 / 8)) + (blockIdx.x >> 3);
  int q = r4 & 3;
  int r = r4 >> 2;
  int b = r / kNX, ix = r - (r / kNX) * kNX;
  int iyb = q * 50;
  size_t s0 = (size_t)r4 * kCap4;
  unsigned n = cnt[r4];
  unsigned ns = min(n, (unsigned)kCap4);

  if (tid < 64) hist[tid] = 0;
  __syncthreads();
  // pass 1: stash + histogram (single global read of the row's entries)
  for (unsigned k = tid; k < ns; k += 512) {
    uint2 a = list[s0 + k];
    slr[k] = a;
    atomicAdd(&hist[(a.x >> 16) - iyb], 1u);
  }
  __syncthreads();
  // wave-0 inclusive scan over 64 bins (no block barriers inside)
  if (tid < 64) {
    unsigned v = hist[tid];
    unsigned sc = v;
#pragma unroll
    for (int o = 1; o < 64; o <<= 1) {
      unsigned y = __shfl_up(sc, o);
      if (tid >= o) sc += y;
    }
    if (tid < 50) {
      off[tid] = sc - v;
      curb[tid] = sc - v;
    }
    if (tid == 0) off[50] = ns;
  }
  __syncthreads();
  // pass 2: reorder LDS -> LDS (no second global read)
  for (unsigned k = tid; k < ns; k += 512) {
    uint2 a = slr[k];
    unsigned pos = atomicAdd(&curb[(a.x >> 16) - iyb], 1u);
    sl[pos] = a;
  }
  __syncthreads();
  // accumulate: group ly = tid>>3 owns bin ly; lane sub = tid&7 owns
  // channels sub*8..sub*8+7 (uint4 = 4 u32 = 8 bf16)
  int ly = tid >> 3, sub = tid & 7;
  if (ly < 50) {
    unsigned k = off[ly], e = off[ly + 1];
    float a0 = 0, a1 = 0, a2 = 0, a3 = 0, a4 = 0, a5 = 0, a6 = 0, a7 = 0;
    for (; k + 4 <= e; k += 4) {        // 4 entries -> 4 lines in flight
      uint2 e0 = sl[k + 0];
      uint2 e1 = sl[k + 1];
      uint2 e2 = sl[k + 2];
      uint2 e3 = sl[k + 3];
      uint4 f0 = ((const uint4*)(featT + ((size_t)(e0.x & 0xFFFFu) << 5)))[sub];
      uint4 f1 = ((const uint4*)(featT + ((size_t)(e1.x & 0xFFFFu) << 5)))[sub];
      uint4 f2 = ((const uint4*)(featT + ((size_t)(e2.x & 0xFFFFu) << 5)))[sub];
      uint4 f3 = ((const uint4*)(featT + ((size_t)(e3.x & 0xFFFFu) << 5)))[sub];
      float w0 = __uint_as_float(e0.y), w1 = __uint_as_float(e1.y);
      float w2 = __uint_as_float(e2.y), w3 = __uint_as_float(e3.y);
      a0 += w0 * __uint_as_float(f0.x << 16);
      a1 += w0 * __uint_as_float(f0.x & 0xFFFF0000u);
      a2 += w0 * __uint_as_float(f0.y << 16);
      a3 += w0 * __uint_as_float(f0.y & 0xFFFF0000u);
      a4 += w0 * __uint_as_float(f0.z << 16);
      a5 += w0 * __uint_as_float(f0.z & 0xFFFF0000u);
      a6 += w0 * __uint_as_float(f0.w << 16);
      a7 += w0 * __uint_as_float(f0.w & 0xFFFF0000u);
      a0 += w1 * __uint_as_float(f1.x << 16);
      a1 += w1 * __uint_as_float(f1.x & 0xFFFF0000u);
      a2 += w1 * __uint_as_float(f1.y << 16);
      a3 += w1 * __uint_as_float(f1.y & 0xFFFF0000u);
      a4 += w1 * __uint_as_float(f1.z << 16);
      a5 += w1 * __uint_as_float(f1.z & 0xFFFF0000u);
      a6 += w1 * __uint_as_float(f1.w << 16);
      a7 += w1 * __uint_as_float(f1.w & 0xFFFF0000u);
      a0 += w2 * __uint_as_float(f2.x << 16);
      a1 += w2 * __uint_as_float(f2.x & 0xFFFF0000u);
      a2 += w2 * __uint_as_float(f2.y << 16);
      a3 += w2 * __uint_as_float(f2.y & 0xFFFF0000u);
      a4 += w2 * __uint_as_float(f2.z << 16);
      a5 += w2 * __uint_as_float(f2.z & 0xFFFF0000u);
      a6 += w2 * __uint_as_float(f2.w << 16);
      a7 += w2 * __uint_as_float(f2.w & 0xFFFF0000u);
      a0 += w3 * __uint_as_float(f3.x << 16);
      a1 += w3 * __uint_as_float(f3.x & 0xFFFF0000u);
      a2 += w3 * __uint_as_float(f3.y << 16);
      a3 += w3 * __uint_as_float(f3.y & 0xFFFF0000u);
      a4 += w3 * __uint_as_float(f3.z << 16);
      a5 += w3 * __uint_as_float(f3.z & 0xFFFF0000u);
      a6 += w3 * __uint_as_float(f3.w << 16);
      a7 += w3 * __uint_as_float(f3.w & 0xFFFF0000u);
    }
    for (; k < e; ++k) {
      uint2 ea = sl[k];
      uint4 fa = ((const uint4*)(featT + ((size_t)(ea.x & 0xFFFFu) << 5)))[sub];
      float wa = __uint_as_float(ea.y);
      a0 += wa * __uint_as_float(fa.x << 16);
      a1 += wa * __uint_as_float(fa.x & 0xFFFF0000u);
      a2 += wa * __uint_as_float(fa.y << 16);
      a3 += wa * __uint_as_float(fa.y & 0xFFFF0000u);
      a4 += wa * __uint_as_float(fa.z << 16);
      a5 += wa * __uint_as_float(fa.z & 0xFFFF0000u);
      a6 += wa * __uint_as_float(fa.w << 16);
      a7 += wa * __uint_as_float(fa.w & 0xFFFF0000u);
    }
    float* dst = &accT[ly * 65 + (sub << 3)];
    dst[0] = a0; dst[1] = a1; dst[2] = a2; dst[3] = a3;
    dst[4] = a4; dst[5] = a5; dst[6] = a6; dst[7] = a7;
  }
  __syncthreads();
  // overflow epilogue (never taken; kept for correctness)
  unsigned ovfn = min(*ovf_cnt, (unsigned)kOvfCap);
  if (ovfn > 0) {
    for (unsigned k = tid; k < ovfn; k += 512) {
      uint4 a = ovf[k];
      if (a.x != (unsigned)r4) continue;
      int lyo = (int)(a.y >> 16) - iyb;
      const uint32_t* fr = featT + ((size_t)(a.y & 0xFFFFu) << 5);
      float w = __uint_as_float(a.z);
      for (int c = 0; c < kC; ++c) {
        uint32_t u = fr[c >> 1];
        float f = __uint_as_float((c & 1) ? (u & 0xFFFF0000u) : (u << 16));
        atomicAdd(&accT[lyo * 65 + c], w * f);
      }
    }
    __syncthreads();
  }
  // coalesced tile store (every cell written -> no output memset)
  float* op = out + (size_t)b * kC * kVox + (size_t)ix * kNX + iyb;
  for (int idx = tid; idx < kC * 50; idx += 512) {
    int c = idx / 50, iy = idx - c * 50;
    op[(size_t)c * kVox + iy] = accT[iy * 65 + c];
  }
}

extern "C" void kernel_launch(void* const* d_in, const int* in_sizes, int n_in,
                              void* d_out, int out_size, void* d_ws,
                              size_t ws_size, hipStream_t stream) {
  const float* feat = (const float*)d_in[0];
  const float* logits = (const float*)d_in[1];
  const float* geom = (const float*)d_in[2];
  float* out = (float*)d_out;

  // Workspace layout (16B-aligned chunks): total ~18.7 MB
  char* w = (char*)d_ws;
  uint2* list = (uint2*)w;         w += (size_t)kRows4 * kCap4 * 8;  // 14.34MB
  uint32_t* featT = (uint32_t*)w;  w += (size_t)kBN * kHW * 32 * 4;  // 4.33MB
  uint4* ovf = (uint4*)w;          w += (size_t)kOvfCap * 16;        // 64KB
  unsigned* cnt = (unsigned*)w;    w += (size_t)kRows4 * 4;
  // ovf_cnt = cnt[kRows4] (zeroed together by lss_zero)
  unsigned* ovf_cnt = cnt + kRows4;

  lss_zero<<<1, 256, 0, stream>>>(cnt);
  lss_fused<<<kFusedBlks, 512, 0, stream>>>(feat, featT, logits, geom, cnt,
                                            list, ovf_cnt, ovf);
  lss_rowgather<<<kRows4, 512, 0, stream>>>(cnt, list, featT, out, ovf_cnt,
                                            ovf);
}